// Round 2
// baseline (574.493 us; speedup 1.0000x reference)
//
#include <hip/hip_runtime.h>

// GCN_72971494359045: 2-layer GCNConv(+self-loops, sym-norm) with PReLU.
// N=50000 nodes, E=800000 edges, dims 128(+8 id)->256->128, all fp32.
//
// Strategy:
//  - edge_index delivered as int32 (harness converts integer inputs to int).
//  - Build CSR by dst per call (histogram -> 1-block scan -> cursor fill).
//  - Layer 1: aggregate x FIRST (dim 128) + per-node norm-sum scalar S,
//    then h1 = prelu(aggx @ W1[0:128] + S*cvec + b1, a1) with
//    cvec[m] = sum_j id[j]*W1[128+j][m] (id columns are node-constant).
//  - Layer 2: h2 = h1 @ W2, then aggregate (dim 128) + b2 + prelu -> out.

constexpr int NN = 50000;
constexpr int NE = 800000;

__global__ void zero_int_kernel(int* __restrict__ p, int n) {
  int i = blockIdx.x * blockDim.x + threadIdx.x;
  if (i < n) p[i] = 0;
}

__global__ void count_deg_kernel(const int* __restrict__ ei, int* __restrict__ cnt) {
  int e = blockIdx.x * blockDim.x + threadIdx.x;
  if (e < NE) {
    int d = ei[NE + e];
    atomicAdd(&cnt[d], 1);
  }
}

__global__ void dinv_kernel(const int* __restrict__ cnt, float* __restrict__ dinv) {
  int i = blockIdx.x * blockDim.x + threadIdx.x;
  if (i < NN) dinv[i] = rsqrtf((float)(cnt[i] + 1));  // +1 self-loop
}

// Single-block exclusive scan of 50000 counts -> offsets (and cursor copy).
__global__ void scan_kernel(const int* __restrict__ cnt, int* __restrict__ offs,
                            int* __restrict__ cursor) {
  __shared__ int sums[1024];
  const int CH = (NN + 1023) / 1024;  // 49
  int t = threadIdx.x;
  int beg = t * CH;
  int end = beg + CH; if (end > NN) end = NN;
  int local = 0;
  for (int i = beg; i < end; ++i) local += cnt[i];
  sums[t] = local;
  __syncthreads();
  for (int off = 1; off < 1024; off <<= 1) {
    int v = (t >= off) ? sums[t - off] : 0;
    __syncthreads();
    sums[t] += v;
    __syncthreads();
  }
  int run = sums[t] - local;  // exclusive prefix
  for (int i = beg; i < end; ++i) {
    offs[i] = run;
    cursor[i] = run;
    run += cnt[i];
  }
  if (t == 0) offs[NN] = sums[1023];
}

__global__ void fill_csr_kernel(const int* __restrict__ ei, int* __restrict__ cursor,
                                int* __restrict__ col) {
  int e = blockIdx.x * blockDim.x + threadIdx.x;
  if (e < NE) {
    int s = ei[e];
    int d = ei[NE + e];
    int pos = atomicAdd(&cursor[d], 1);
    col[pos] = s;
  }
}

__global__ void cvec_kernel(const float* __restrict__ idv, const float* __restrict__ W1,
                            float* __restrict__ cvec) {
  int m = threadIdx.x;  // 256
  float c = 0.f;
#pragma unroll
  for (int j = 0; j < 8; ++j) c += idv[j] * W1[(128 + j) * 256 + m];
  cvec[m] = c;
}

// One block (128 threads) per dst node: aggregate x rows + norm-sum scalar.
__global__ void agg_first_kernel(const float* __restrict__ x, const float* __restrict__ dinv,
                                 const int* __restrict__ offs, const int* __restrict__ col,
                                 float* __restrict__ aggx, float* __restrict__ S) {
  int d = blockIdx.x;
  int t = threadIdx.x;  // 0..127
  float dd = dinv[d];
  float w0 = dd * dd;                       // self-loop norm
  float acc = x[(size_t)d * 128 + t] * w0;
  float snorm = w0;
  int beg = offs[d], end = offs[d + 1];
  for (int p = beg; p < end; ++p) {
    int s = col[p];
    float w = dinv[s] * dd;
    acc += x[(size_t)s * 128 + t] * w;
    snorm += w;
  }
  aggx[(size_t)d * 128 + t] = acc;
  if (t == 0) S[d] = snorm;
}

// One block (128 threads) per dst node: aggregate h2 rows, + bias + prelu.
__global__ void agg_second_kernel(const float* __restrict__ h2, const float* __restrict__ dinv,
                                  const int* __restrict__ offs, const int* __restrict__ col,
                                  const float* __restrict__ b2, const float* __restrict__ a2,
                                  float* __restrict__ out) {
  int d = blockIdx.x;
  int t = threadIdx.x;  // 0..127
  float dd = dinv[d];
  float acc = h2[(size_t)d * 128 + t] * (dd * dd);
  int beg = offs[d], end = offs[d + 1];
  for (int p = beg; p < end; ++p) {
    int s = col[p];
    acc += h2[(size_t)s * 128 + t] * (dinv[s] * dd);
  }
  float v = acc + b2[t];
  out[(size_t)d * 128 + t] = (v >= 0.f) ? v : a2[t] * v;
}

// fp32 tiled GEMM: C[M,N] = A[M,K] @ B[K,N]; BM=BN=64, BK=16, 256 thr, 4x4 microtile.
// LDS tiles unpadded (row stride 64 floats = 256 B) so float4 LDS ops stay
// 16B-aligned; float4 accesses are <=2-way bank-aliased (free on gfx950).
// MODE 1: fused epilogue v += S[r]*cvec[c] + bias[c]; prelu(alpha). MODE 0: plain store.
template <int MODE>
__global__ __launch_bounds__(256) void gemm_kernel(
    const float* __restrict__ A, const float* __restrict__ B, float* __restrict__ C,
    int M, int N, int K,
    const float* __restrict__ Svec, const float* __restrict__ cvec,
    const float* __restrict__ bias, const float* __restrict__ alpha) {
  constexpr int BM = 64, BN = 64, BK = 16;
  __shared__ float As[BK][BM];  // k-major (transposed on store)
  __shared__ float Bs[BK][BN];
  int t = threadIdx.x;
  int tx = t & 15, ty = t >> 4;
  int row0 = blockIdx.x * BM, col0 = blockIdx.y * BN;
  int arow = t >> 2;         // 0..63
  int ak = (t & 3) << 2;     // 0,4,8,12
  int brow = t >> 4;         // 0..15
  int bc = (t & 15) << 2;    // 0..60
  float acc[4][4] = {};
  for (int k0 = 0; k0 < K; k0 += BK) {
    float4 av = make_float4(0.f, 0.f, 0.f, 0.f);
    int gr = row0 + arow;
    if (gr < M) av = *(const float4*)(A + (size_t)gr * K + k0 + ak);
    As[ak + 0][arow] = av.x;
    As[ak + 1][arow] = av.y;
    As[ak + 2][arow] = av.z;
    As[ak + 3][arow] = av.w;
    float4 bv = *(const float4*)(B + (size_t)(k0 + brow) * N + col0 + bc);
    *(float4*)&Bs[brow][bc] = bv;
    __syncthreads();
#pragma unroll
    for (int kk = 0; kk < BK; ++kk) {
      float4 a = *(const float4*)&As[kk][ty << 2];
      float4 b = *(const float4*)&Bs[kk][tx << 2];
      acc[0][0] += a.x * b.x; acc[0][1] += a.x * b.y; acc[0][2] += a.x * b.z; acc[0][3] += a.x * b.w;
      acc[1][0] += a.y * b.x; acc[1][1] += a.y * b.y; acc[1][2] += a.y * b.z; acc[1][3] += a.y * b.w;
      acc[2][0] += a.z * b.x; acc[2][1] += a.z * b.y; acc[2][2] += a.z * b.z; acc[2][3] += a.z * b.w;
      acc[3][0] += a.w * b.x; acc[3][1] += a.w * b.y; acc[3][2] += a.w * b.z; acc[3][3] += a.w * b.w;
    }
    __syncthreads();
  }
#pragma unroll
  for (int i = 0; i < 4; ++i) {
    int r = row0 + (ty << 2) + i;
    if (r >= M) continue;
    float s = (MODE == 1) ? Svec[r] : 0.f;
    float vv[4];
#pragma unroll
    for (int j = 0; j < 4; ++j) {
      int c = col0 + (tx << 2) + j;
      float v = acc[i][j];
      if (MODE == 1) {
        v += s * cvec[c] + bias[c];
        v = (v >= 0.f) ? v : alpha[c] * v;
      }
      vv[j] = v;
    }
    *(float4*)(C + (size_t)r * N + col0 + (tx << 2)) =
        make_float4(vv[0], vv[1], vv[2], vv[3]);
  }
}

extern "C" void kernel_launch(void* const* d_in, const int* in_sizes, int n_in,
                              void* d_out, int out_size, void* d_ws, size_t ws_size,
                              hipStream_t stream) {
  const float* x = (const float*)d_in[0];
  const int* ei = (const int*)d_in[1];   // int inputs arrive as int32
  const float* idv = (const float*)d_in[2];
  const float* W1 = (const float*)d_in[3];
  const float* b1 = (const float*)d_in[4];
  const float* a1 = (const float*)d_in[5];
  const float* W2 = (const float*)d_in[6];
  const float* b2 = (const float*)d_in[7];
  const float* a2 = (const float*)d_in[8];
  float* out = (float*)d_out;

  char* w = (char*)d_ws;
  size_t off = 0;
  auto alloc = [&](size_t bytes) -> void* {
    void* p = w + off;
    off += bytes;
    off = (off + 255) & ~(size_t)255;
    return p;
  };
  int* degcnt = (int*)alloc((size_t)NN * 4);
  float* dinv = (float*)alloc((size_t)NN * 4);
  float* Svec = (float*)alloc((size_t)NN * 4);
  int* offs = (int*)alloc((size_t)(NN + 1) * 4);
  int* cursor = (int*)alloc((size_t)NN * 4);
  int* col = (int*)alloc((size_t)NE * 4);
  float* cvec = (float*)alloc(256 * 4);
  float* aggx = (float*)alloc((size_t)NN * 128 * 4);
  float* h1 = (float*)alloc((size_t)NN * 256 * 4);
  float* h2 = (float*)alloc((size_t)NN * 128 * 4);

  zero_int_kernel<<<(NN + 255) / 256, 256, 0, stream>>>(degcnt, NN);
  count_deg_kernel<<<(NE + 255) / 256, 256, 0, stream>>>(ei, degcnt);
  dinv_kernel<<<(NN + 255) / 256, 256, 0, stream>>>(degcnt, dinv);
  scan_kernel<<<1, 1024, 0, stream>>>(degcnt, offs, cursor);
  fill_csr_kernel<<<(NE + 255) / 256, 256, 0, stream>>>(ei, cursor, col);
  cvec_kernel<<<1, 256, 0, stream>>>(idv, W1, cvec);

  agg_first_kernel<<<NN, 128, 0, stream>>>(x, dinv, offs, col, aggx, Svec);

  dim3 g1((NN + 63) / 64, 256 / 64);
  gemm_kernel<1><<<g1, 256, 0, stream>>>(aggx, W1, h1, NN, 256, 128, Svec, cvec, b1, a1);

  dim3 g2((NN + 63) / 64, 128 / 64);
  gemm_kernel<0><<<g2, 256, 0, stream>>>(h1, W2, h2, NN, 128, 256, nullptr, nullptr, nullptr, nullptr);

  agg_second_kernel<<<NN, 128, 0, stream>>>(h2, dinv, offs, col, b2, a2, out);
}

// Round 3
// 480.340 us; speedup vs baseline: 1.1960x; 1.1960x over previous
//
#include <hip/hip_runtime.h>

// GCN_72971494359045: 2-layer GCNConv(+self-loops, sym-norm) with PReLU.
// N=50000 nodes, E=800000 edges, dims 128(+8 id)->256->128, all fp32.
//
// R2: replaced 1-block scan (110 us, latency-bound on 1 CU) with a
// 3-kernel hierarchical scan (~8 us).

constexpr int NN = 50000;
constexpr int NE = 800000;
constexpr int SCAN_CHUNK = 1024;                       // elems per block
constexpr int SCAN_NBLK = (NN + SCAN_CHUNK - 1) / SCAN_CHUNK;  // 49

__global__ void zero_int_kernel(int* __restrict__ p, int n) {
  int i = blockIdx.x * blockDim.x + threadIdx.x;
  if (i < n) p[i] = 0;
}

__global__ void count_deg_kernel(const int* __restrict__ ei, int* __restrict__ cnt) {
  int e = blockIdx.x * blockDim.x + threadIdx.x;
  if (e < NE) {
    int d = ei[NE + e];
    atomicAdd(&cnt[d], 1);
  }
}

__global__ void dinv_kernel(const int* __restrict__ cnt, float* __restrict__ dinv) {
  int i = blockIdx.x * blockDim.x + threadIdx.x;
  if (i < NN) dinv[i] = rsqrtf((float)(cnt[i] + 1));  // +1 self-loop
}

// --- hierarchical scan: 49 blocks x 1024 elems ---
__global__ void blocksum_kernel(const int* __restrict__ cnt, int* __restrict__ bsum) {
  __shared__ int sm[256];
  int b = blockIdx.x, t = threadIdx.x;
  int base = b * SCAN_CHUNK + t * 4;
  int s = 0;
#pragma unroll
  for (int j = 0; j < 4; ++j) {
    int i = base + j;
    if (i < NN) s += cnt[i];
  }
  sm[t] = s;
  __syncthreads();
  for (int off = 128; off > 0; off >>= 1) {
    if (t < off) sm[t] += sm[t + off];
    __syncthreads();
  }
  if (t == 0) bsum[b] = sm[0];
}

__global__ void scan_bsum_kernel(const int* __restrict__ bsum, int* __restrict__ bbase) {
  int t = threadIdx.x;  // 64
  int v = (t < SCAN_NBLK) ? bsum[t] : 0;
  for (int d = 1; d < 64; d <<= 1) {
    int u = __shfl_up(v, d, 64);
    if (t >= d) v += u;
  }
  int ex = __shfl_up(v, 1, 64);
  if (t == 0) ex = 0;
  if (t < SCAN_NBLK) bbase[t] = ex;
}

__global__ void scan_final_kernel(const int* __restrict__ cnt, const int* __restrict__ bbase,
                                  int* __restrict__ offs, int* __restrict__ cursor) {
  __shared__ int sm[256];
  int b = blockIdx.x, t = threadIdx.x;
  int base = b * SCAN_CHUNK + t * 4;
  int c[4];
  int s = 0;
#pragma unroll
  for (int j = 0; j < 4; ++j) {
    int i = base + j;
    c[j] = (i < NN) ? cnt[i] : 0;
    s += c[j];
  }
  sm[t] = s;
  __syncthreads();
  for (int off = 1; off < 256; off <<= 1) {
    int v = (t >= off) ? sm[t - off] : 0;
    __syncthreads();
    sm[t] += v;
    __syncthreads();
  }
  int run = bbase[b] + sm[t] - s;  // exclusive prefix for this thread
#pragma unroll
  for (int j = 0; j < 4; ++j) {
    int i = base + j;
    if (i < NN) {
      offs[i] = run;
      cursor[i] = run;
      run += c[j];
    }
  }
  if (b == 0 && t == 0) offs[NN] = NE;  // total incl. nothing: constant
}

__global__ void fill_csr_kernel(const int* __restrict__ ei, int* __restrict__ cursor,
                                int* __restrict__ col) {
  int e = blockIdx.x * blockDim.x + threadIdx.x;
  if (e < NE) {
    int s = ei[e];
    int d = ei[NE + e];
    int pos = atomicAdd(&cursor[d], 1);
    col[pos] = s;
  }
}

__global__ void cvec_kernel(const float* __restrict__ idv, const float* __restrict__ W1,
                            float* __restrict__ cvec) {
  int m = threadIdx.x;  // 256
  float c = 0.f;
#pragma unroll
  for (int j = 0; j < 8; ++j) c += idv[j] * W1[(128 + j) * 256 + m];
  cvec[m] = c;
}

// One block (128 threads) per dst node: aggregate x rows + norm-sum scalar.
__global__ void agg_first_kernel(const float* __restrict__ x, const float* __restrict__ dinv,
                                 const int* __restrict__ offs, const int* __restrict__ col,
                                 float* __restrict__ aggx, float* __restrict__ S) {
  int d = blockIdx.x;
  int t = threadIdx.x;  // 0..127
  float dd = dinv[d];
  float w0 = dd * dd;                       // self-loop norm
  float acc = x[(size_t)d * 128 + t] * w0;
  float snorm = w0;
  int beg = offs[d], end = offs[d + 1];
  for (int p = beg; p < end; ++p) {
    int s = col[p];
    float w = dinv[s] * dd;
    acc += x[(size_t)s * 128 + t] * w;
    snorm += w;
  }
  aggx[(size_t)d * 128 + t] = acc;
  if (t == 0) S[d] = snorm;
}

// One block (128 threads) per dst node: aggregate h2 rows, + bias + prelu.
__global__ void agg_second_kernel(const float* __restrict__ h2, const float* __restrict__ dinv,
                                  const int* __restrict__ offs, const int* __restrict__ col,
                                  const float* __restrict__ b2, const float* __restrict__ a2,
                                  float* __restrict__ out) {
  int d = blockIdx.x;
  int t = threadIdx.x;  // 0..127
  float dd = dinv[d];
  float acc = h2[(size_t)d * 128 + t] * (dd * dd);
  int beg = offs[d], end = offs[d + 1];
  for (int p = beg; p < end; ++p) {
    int s = col[p];
    acc += h2[(size_t)s * 128 + t] * (dinv[s] * dd);
  }
  float v = acc + b2[t];
  out[(size_t)d * 128 + t] = (v >= 0.f) ? v : a2[t] * v;
}

// fp32 tiled GEMM: C[M,N] = A[M,K] @ B[K,N]; BM=BN=64, BK=16, 256 thr, 4x4 microtile.
// LDS tiles unpadded (row stride 64 floats = 256 B) so float4 LDS ops stay
// 16B-aligned; float4 accesses are <=2-way bank-aliased (free on gfx950).
// MODE 1: fused epilogue v += S[r]*cvec[c] + bias[c]; prelu(alpha). MODE 0: plain store.
template <int MODE>
__global__ __launch_bounds__(256) void gemm_kernel(
    const float* __restrict__ A, const float* __restrict__ B, float* __restrict__ C,
    int M, int N, int K,
    const float* __restrict__ Svec, const float* __restrict__ cvec,
    const float* __restrict__ bias, const float* __restrict__ alpha) {
  constexpr int BM = 64, BN = 64, BK = 16;
  __shared__ float As[BK][BM];  // k-major (transposed on store)
  __shared__ float Bs[BK][BN];
  int t = threadIdx.x;
  int tx = t & 15, ty = t >> 4;
  int row0 = blockIdx.x * BM, col0 = blockIdx.y * BN;
  int arow = t >> 2;         // 0..63
  int ak = (t & 3) << 2;     // 0,4,8,12
  int brow = t >> 4;         // 0..15
  int bc = (t & 15) << 2;    // 0..60
  float acc[4][4] = {};
  for (int k0 = 0; k0 < K; k0 += BK) {
    float4 av = make_float4(0.f, 0.f, 0.f, 0.f);
    int gr = row0 + arow;
    if (gr < M) av = *(const float4*)(A + (size_t)gr * K + k0 + ak);
    As[ak + 0][arow] = av.x;
    As[ak + 1][arow] = av.y;
    As[ak + 2][arow] = av.z;
    As[ak + 3][arow] = av.w;
    float4 bv = *(const float4*)(B + (size_t)(k0 + brow) * N + col0 + bc);
    *(float4*)&Bs[brow][bc] = bv;
    __syncthreads();
#pragma unroll
    for (int kk = 0; kk < BK; ++kk) {
      float4 a = *(const float4*)&As[kk][ty << 2];
      float4 b = *(const float4*)&Bs[kk][tx << 2];
      acc[0][0] += a.x * b.x; acc[0][1] += a.x * b.y; acc[0][2] += a.x * b.z; acc[0][3] += a.x * b.w;
      acc[1][0] += a.y * b.x; acc[1][1] += a.y * b.y; acc[1][2] += a.y * b.z; acc[1][3] += a.y * b.w;
      acc[2][0] += a.z * b.x; acc[2][1] += a.z * b.y; acc[2][2] += a.z * b.z; acc[2][3] += a.z * b.w;
      acc[3][0] += a.w * b.x; acc[3][1] += a.w * b.y; acc[3][2] += a.w * b.z; acc[3][3] += a.w * b.w;
    }
    __syncthreads();
  }
#pragma unroll
  for (int i = 0; i < 4; ++i) {
    int r = row0 + (ty << 2) + i;
    if (r >= M) continue;
    float s = (MODE == 1) ? Svec[r] : 0.f;
    float vv[4];
#pragma unroll
    for (int j = 0; j < 4; ++j) {
      int c = col0 + (tx << 2) + j;
      float v = acc[i][j];
      if (MODE == 1) {
        v += s * cvec[c] + bias[c];
        v = (v >= 0.f) ? v : alpha[c] * v;
      }
      vv[j] = v;
    }
    *(float4*)(C + (size_t)r * N + col0 + (tx << 2)) =
        make_float4(vv[0], vv[1], vv[2], vv[3]);
  }
}

extern "C" void kernel_launch(void* const* d_in, const int* in_sizes, int n_in,
                              void* d_out, int out_size, void* d_ws, size_t ws_size,
                              hipStream_t stream) {
  const float* x = (const float*)d_in[0];
  const int* ei = (const int*)d_in[1];   // int inputs arrive as int32
  const float* idv = (const float*)d_in[2];
  const float* W1 = (const float*)d_in[3];
  const float* b1 = (const float*)d_in[4];
  const float* a1 = (const float*)d_in[5];
  const float* W2 = (const float*)d_in[6];
  const float* b2 = (const float*)d_in[7];
  const float* a2 = (const float*)d_in[8];
  float* out = (float*)d_out;

  char* w = (char*)d_ws;
  size_t off = 0;
  auto alloc = [&](size_t bytes) -> void* {
    void* p = w + off;
    off += bytes;
    off = (off + 255) & ~(size_t)255;
    return p;
  };
  int* degcnt = (int*)alloc((size_t)NN * 4);
  float* dinv = (float*)alloc((size_t)NN * 4);
  float* Svec = (float*)alloc((size_t)NN * 4);
  int* offs = (int*)alloc((size_t)(NN + 1) * 4);
  int* cursor = (int*)alloc((size_t)NN * 4);
  int* col = (int*)alloc((size_t)NE * 4);
  float* cvec = (float*)alloc(256 * 4);
  int* bsum = (int*)alloc((size_t)SCAN_NBLK * 4);
  int* bbase = (int*)alloc((size_t)SCAN_NBLK * 4);
  float* aggx = (float*)alloc((size_t)NN * 128 * 4);
  float* h1 = (float*)alloc((size_t)NN * 256 * 4);
  float* h2 = (float*)alloc((size_t)NN * 128 * 4);

  zero_int_kernel<<<(NN + 255) / 256, 256, 0, stream>>>(degcnt, NN);
  count_deg_kernel<<<(NE + 255) / 256, 256, 0, stream>>>(ei, degcnt);
  dinv_kernel<<<(NN + 255) / 256, 256, 0, stream>>>(degcnt, dinv);
  blocksum_kernel<<<SCAN_NBLK, 256, 0, stream>>>(degcnt, bsum);
  scan_bsum_kernel<<<1, 64, 0, stream>>>(bsum, bbase);
  scan_final_kernel<<<SCAN_NBLK, 256, 0, stream>>>(degcnt, bbase, offs, cursor);
  fill_csr_kernel<<<(NE + 255) / 256, 256, 0, stream>>>(ei, cursor, col);
  cvec_kernel<<<1, 256, 0, stream>>>(idv, W1, cvec);

  agg_first_kernel<<<NN, 128, 0, stream>>>(x, dinv, offs, col, aggx, Svec);

  dim3 g1((NN + 63) / 64, 256 / 64);
  gemm_kernel<1><<<g1, 256, 0, stream>>>(aggx, W1, h1, NN, 256, 128, Svec, cvec, b1, a1);

  dim3 g2((NN + 63) / 64, 128 / 64);
  gemm_kernel<0><<<g2, 256, 0, stream>>>(h1, W2, h2, NN, 128, 256, nullptr, nullptr, nullptr, nullptr);

  agg_second_kernel<<<NN, 128, 0, stream>>>(h2, dinv, offs, col, b2, a2, out);
}

// Round 4
// 451.902 us; speedup vs baseline: 1.2713x; 1.0629x over previous
//
#include <hip/hip_runtime.h>

// GCN_72971494359045: 2-layer GCNConv(+self-loops, sym-norm) with PReLU.
// N=50000 nodes, E=800000 edges, dims 128(+8 id)->256->128, all fp32.
//
// R3: gather kernels rebuilt for MLP: float4/lane, wave-per-node, 2 edges
// per iter (half-wave each) x2 unroll; inputs pre-scaled by dinv so the
// edge loop is a pure sum; Sum(dinv[s]) via atomics in fill_csr.

constexpr int NN = 50000;
constexpr int NE = 800000;
constexpr int SCAN_CHUNK = 1024;                       // elems per block
constexpr int SCAN_NBLK = (NN + SCAN_CHUNK - 1) / SCAN_CHUNK;  // 49

__global__ void zero2_kernel(int* __restrict__ p0, float* __restrict__ p1, int n) {
  int i = blockIdx.x * blockDim.x + threadIdx.x;
  if (i < n) { p0[i] = 0; p1[i] = 0.f; }
}

__global__ void count_deg_kernel(const int* __restrict__ ei, int* __restrict__ cnt) {
  int e = blockIdx.x * blockDim.x + threadIdx.x;
  if (e < NE) {
    int d = ei[NE + e];
    atomicAdd(&cnt[d], 1);
  }
}

__global__ void dinv_kernel(const int* __restrict__ cnt, float* __restrict__ dinv) {
  int i = blockIdx.x * blockDim.x + threadIdx.x;
  if (i < NN) dinv[i] = rsqrtf((float)(cnt[i] + 1));  // +1 self-loop
}

// --- hierarchical scan: 49 blocks x 1024 elems ---
__global__ void blocksum_kernel(const int* __restrict__ cnt, int* __restrict__ bsum) {
  __shared__ int sm[256];
  int b = blockIdx.x, t = threadIdx.x;
  int base = b * SCAN_CHUNK + t * 4;
  int s = 0;
#pragma unroll
  for (int j = 0; j < 4; ++j) {
    int i = base + j;
    if (i < NN) s += cnt[i];
  }
  sm[t] = s;
  __syncthreads();
  for (int off = 128; off > 0; off >>= 1) {
    if (t < off) sm[t] += sm[t + off];
    __syncthreads();
  }
  if (t == 0) bsum[b] = sm[0];
}

__global__ void scan_bsum_kernel(const int* __restrict__ bsum, int* __restrict__ bbase) {
  int t = threadIdx.x;  // 64
  int v = (t < SCAN_NBLK) ? bsum[t] : 0;
  for (int d = 1; d < 64; d <<= 1) {
    int u = __shfl_up(v, d, 64);
    if (t >= d) v += u;
  }
  int ex = __shfl_up(v, 1, 64);
  if (t == 0) ex = 0;
  if (t < SCAN_NBLK) bbase[t] = ex;
}

__global__ void scan_final_kernel(const int* __restrict__ cnt, const int* __restrict__ bbase,
                                  int* __restrict__ offs, int* __restrict__ cursor) {
  __shared__ int sm[256];
  int b = blockIdx.x, t = threadIdx.x;
  int base = b * SCAN_CHUNK + t * 4;
  int c[4];
  int s = 0;
#pragma unroll
  for (int j = 0; j < 4; ++j) {
    int i = base + j;
    c[j] = (i < NN) ? cnt[i] : 0;
    s += c[j];
  }
  sm[t] = s;
  __syncthreads();
  for (int off = 1; off < 256; off <<= 1) {
    int v = (t >= off) ? sm[t - off] : 0;
    __syncthreads();
    sm[t] += v;
    __syncthreads();
  }
  int run = bbase[b] + sm[t] - s;  // exclusive prefix for this thread
#pragma unroll
  for (int j = 0; j < 4; ++j) {
    int i = base + j;
    if (i < NN) {
      offs[i] = run;
      cursor[i] = run;
      run += c[j];
    }
  }
  if (b == 0 && t == 0) offs[NN] = NE;
}

// CSR fill + per-dst sum of dinv[src] (for the id-columns epilogue term).
__global__ void fill_csr_kernel(const int* __restrict__ ei, int* __restrict__ cursor,
                                int* __restrict__ col, const float* __restrict__ dinv,
                                float* __restrict__ Ssum) {
  int e = blockIdx.x * blockDim.x + threadIdx.x;
  if (e < NE) {
    int s = ei[e];
    int d = ei[NE + e];
    int pos = atomicAdd(&cursor[d], 1);
    col[pos] = s;
    atomicAdd(&Ssum[d], dinv[s]);
  }
}

__global__ void cvec_kernel(const float* __restrict__ idv, const float* __restrict__ W1,
                            float* __restrict__ cvec) {
  int m = threadIdx.x;  // 256
  float c = 0.f;
#pragma unroll
  for (int j = 0; j < 8; ++j) c += idv[j] * W1[(128 + j) * 256 + m];
  cvec[m] = c;
}

// xs[n,:] = x[n,:] * dinv[n]  (float4 elementwise)
__global__ void scale_x_kernel(const float* __restrict__ x, const float* __restrict__ dinv,
                               float* __restrict__ xs) {
  int i = blockIdx.x * blockDim.x + threadIdx.x;  // over NN*32 float4s
  if (i < NN * 32) {
    float dd = dinv[i >> 5];
    float4 v = ((const float4*)x)[i];
    v.x *= dd; v.y *= dd; v.z *= dd; v.w *= dd;
    ((float4*)xs)[i] = v;
  }
}

// Wave per node; 32 lanes x float4 cover the 128-wide row; the two 32-lane
// halves take alternating edges; x2 unroll => 4 row-loads in flight/wave.
// MODE 0 (layer1): in = xs (pre-scaled); out = dd*(self+sum); S[d]=dd*(dd+Ssum[d]).
// MODE 1 (layer2): in = h2s (pre-scaled); out = prelu(dd*(self+sum)+b, a).
template <int MODE>
__global__ __launch_bounds__(256) void agg_kernel(
    const float* __restrict__ in, const float* __restrict__ dinv,
    const int* __restrict__ offs, const int* __restrict__ col,
    const float* __restrict__ Ssum, float* __restrict__ S,
    const float* __restrict__ bias, const float* __restrict__ alpha,
    float* __restrict__ out) {
  const float4* in4 = (const float4*)in;
  int t = threadIdx.x;
  int node = blockIdx.x * 4 + (t >> 6);  // 4 waves/block, 1 node/wave
  int lane = t & 63;
  int r = lane & 31;
  int half = lane >> 5;
  int beg = offs[node], end = offs[node + 1];

  float4 a0 = make_float4(0.f, 0.f, 0.f, 0.f);
  float4 a1 = make_float4(0.f, 0.f, 0.f, 0.f);
  int p = beg + half;
  for (; p + 2 < end; p += 4) {
    int s0 = col[p];
    int s1 = col[p + 2];
    float4 v0 = in4[(size_t)s0 * 32 + r];
    float4 v1 = in4[(size_t)s1 * 32 + r];
    a0.x += v0.x; a0.y += v0.y; a0.z += v0.z; a0.w += v0.w;
    a1.x += v1.x; a1.y += v1.y; a1.z += v1.z; a1.w += v1.w;
  }
  if (p < end) {
    float4 v0 = in4[(size_t)col[p] * 32 + r];
    a0.x += v0.x; a0.y += v0.y; a0.z += v0.z; a0.w += v0.w;
  }
  float4 acc = make_float4(a0.x + a1.x, a0.y + a1.y, a0.z + a1.z, a0.w + a1.w);
  acc.x += __shfl_xor(acc.x, 32);
  acc.y += __shfl_xor(acc.y, 32);
  acc.z += __shfl_xor(acc.z, 32);
  acc.w += __shfl_xor(acc.w, 32);

  float dd = dinv[node];
  if (half == 0) {
    float4 self = in4[(size_t)node * 32 + r];
    acc.x = dd * (acc.x + self.x);
    acc.y = dd * (acc.y + self.y);
    acc.z = dd * (acc.z + self.z);
    acc.w = dd * (acc.w + self.w);
    if (MODE == 1) {
      float4 b = ((const float4*)bias)[r];
      float4 al = ((const float4*)alpha)[r];
      acc.x += b.x; acc.y += b.y; acc.z += b.z; acc.w += b.w;
      acc.x = (acc.x >= 0.f) ? acc.x : al.x * acc.x;
      acc.y = (acc.y >= 0.f) ? acc.y : al.y * acc.y;
      acc.z = (acc.z >= 0.f) ? acc.z : al.z * acc.z;
      acc.w = (acc.w >= 0.f) ? acc.w : al.w * acc.w;
    }
    ((float4*)out)[(size_t)node * 32 + r] = acc;
    if (MODE == 0 && r == 0) S[node] = dd * (dd + Ssum[node]);
  }
}

// fp32 tiled GEMM: C[M,N] = A[M,K] @ B[K,N]; BM=BN=64, BK=16, 256 thr, 4x4 microtile.
// MODE 1: epilogue v += S[row]*cvec[c] + bias[c]; prelu(alpha).
// MODE 2: epilogue v *= rowscale[row]  (pre-scale for the layer-2 gather).
template <int MODE>
__global__ __launch_bounds__(256) void gemm_kernel(
    const float* __restrict__ A, const float* __restrict__ B, float* __restrict__ C,
    int M, int N, int K,
    const float* __restrict__ Svec, const float* __restrict__ cvec,
    const float* __restrict__ bias, const float* __restrict__ alpha,
    const float* __restrict__ rowscale) {
  constexpr int BM = 64, BN = 64, BK = 16;
  __shared__ float As[BK][BM];  // k-major (transposed on store)
  __shared__ float Bs[BK][BN];
  int t = threadIdx.x;
  int tx = t & 15, ty = t >> 4;
  int row0 = blockIdx.x * BM, col0 = blockIdx.y * BN;
  int arow = t >> 2;         // 0..63
  int ak = (t & 3) << 2;     // 0,4,8,12
  int brow = t >> 4;         // 0..15
  int bc = (t & 15) << 2;    // 0..60
  float acc[4][4] = {};
  for (int k0 = 0; k0 < K; k0 += BK) {
    float4 av = make_float4(0.f, 0.f, 0.f, 0.f);
    int gr = row0 + arow;
    if (gr < M) av = *(const float4*)(A + (size_t)gr * K + k0 + ak);
    As[ak + 0][arow] = av.x;
    As[ak + 1][arow] = av.y;
    As[ak + 2][arow] = av.z;
    As[ak + 3][arow] = av.w;
    float4 bv = *(const float4*)(B + (size_t)(k0 + brow) * N + col0 + bc);
    *(float4*)&Bs[brow][bc] = bv;
    __syncthreads();
#pragma unroll
    for (int kk = 0; kk < BK; ++kk) {
      float4 a = *(const float4*)&As[kk][ty << 2];
      float4 b = *(const float4*)&Bs[kk][tx << 2];
      acc[0][0] += a.x * b.x; acc[0][1] += a.x * b.y; acc[0][2] += a.x * b.z; acc[0][3] += a.x * b.w;
      acc[1][0] += a.y * b.x; acc[1][1] += a.y * b.y; acc[1][2] += a.y * b.z; acc[1][3] += a.y * b.w;
      acc[2][0] += a.z * b.x; acc[2][1] += a.z * b.y; acc[2][2] += a.z * b.z; acc[2][3] += a.z * b.w;
      acc[3][0] += a.w * b.x; acc[3][1] += a.w * b.y; acc[3][2] += a.w * b.z; acc[3][3] += a.w * b.w;
    }
    __syncthreads();
  }
#pragma unroll
  for (int i = 0; i < 4; ++i) {
    int r = row0 + (ty << 2) + i;
    if (r >= M) continue;
    float s = (MODE == 1) ? Svec[r] : ((MODE == 2) ? rowscale[r] : 0.f);
    float vv[4];
#pragma unroll
    for (int j = 0; j < 4; ++j) {
      int c = col0 + (tx << 2) + j;
      float v = acc[i][j];
      if (MODE == 1) {
        v += s * cvec[c] + bias[c];
        v = (v >= 0.f) ? v : alpha[c] * v;
      } else if (MODE == 2) {
        v *= s;
      }
      vv[j] = v;
    }
    *(float4*)(C + (size_t)r * N + col0 + (tx << 2)) =
        make_float4(vv[0], vv[1], vv[2], vv[3]);
  }
}

extern "C" void kernel_launch(void* const* d_in, const int* in_sizes, int n_in,
                              void* d_out, int out_size, void* d_ws, size_t ws_size,
                              hipStream_t stream) {
  const float* x = (const float*)d_in[0];
  const int* ei = (const int*)d_in[1];
  const float* idv = (const float*)d_in[2];
  const float* W1 = (const float*)d_in[3];
  const float* b1 = (const float*)d_in[4];
  const float* a1 = (const float*)d_in[5];
  const float* W2 = (const float*)d_in[6];
  const float* b2 = (const float*)d_in[7];
  const float* a2 = (const float*)d_in[8];
  float* out = (float*)d_out;

  char* w = (char*)d_ws;
  size_t off = 0;
  auto alloc = [&](size_t bytes) -> void* {
    void* p = w + off;
    off += bytes;
    off = (off + 255) & ~(size_t)255;
    return p;
  };
  int* degcnt = (int*)alloc((size_t)NN * 4);
  float* dinv = (float*)alloc((size_t)NN * 4);
  float* Ssum = (float*)alloc((size_t)NN * 4);
  float* Svec = (float*)alloc((size_t)NN * 4);
  int* offs = (int*)alloc((size_t)(NN + 1) * 4);
  int* cursor = (int*)alloc((size_t)NN * 4);
  int* col = (int*)alloc((size_t)NE * 4);
  float* cvec = (float*)alloc(256 * 4);
  int* bsum = (int*)alloc((size_t)SCAN_NBLK * 4);
  int* bbase = (int*)alloc((size_t)SCAN_NBLK * 4);
  float* xs = (float*)alloc((size_t)NN * 128 * 4);
  float* aggx = (float*)alloc((size_t)NN * 128 * 4);
  float* h1 = (float*)alloc((size_t)NN * 256 * 4);
  float* h2s = (float*)alloc((size_t)NN * 128 * 4);

  zero2_kernel<<<(NN + 255) / 256, 256, 0, stream>>>(degcnt, Ssum, NN);
  count_deg_kernel<<<(NE + 255) / 256, 256, 0, stream>>>(ei, degcnt);
  dinv_kernel<<<(NN + 255) / 256, 256, 0, stream>>>(degcnt, dinv);
  blocksum_kernel<<<SCAN_NBLK, 256, 0, stream>>>(degcnt, bsum);
  scan_bsum_kernel<<<1, 64, 0, stream>>>(bsum, bbase);
  scan_final_kernel<<<SCAN_NBLK, 256, 0, stream>>>(degcnt, bbase, offs, cursor);
  fill_csr_kernel<<<(NE + 255) / 256, 256, 0, stream>>>(ei, cursor, col, dinv, Ssum);
  cvec_kernel<<<1, 256, 0, stream>>>(idv, W1, cvec);
  scale_x_kernel<<<(NN * 32 + 255) / 256, 256, 0, stream>>>(x, dinv, xs);

  // layer-1 aggregate (pure sum over pre-scaled rows)
  agg_kernel<0><<<NN / 4, 256, 0, stream>>>(xs, dinv, offs, col, Ssum, Svec,
                                            nullptr, nullptr, aggx);

  dim3 g1((NN + 63) / 64, 256 / 64);
  gemm_kernel<1><<<g1, 256, 0, stream>>>(aggx, W1, h1, NN, 256, 128, Svec, cvec, b1, a1, nullptr);

  dim3 g2((NN + 63) / 64, 128 / 64);
  gemm_kernel<2><<<g2, 256, 0, stream>>>(h1, W2, h2s, NN, 128, 256, nullptr, nullptr, nullptr,
                                         nullptr, dinv);

  // layer-2 aggregate + bias + prelu
  agg_kernel<1><<<NN / 4, 256, 0, stream>>>(h2s, dinv, offs, col, nullptr, nullptr,
                                            b2, a2, out);
}

// Round 5
// 377.113 us; speedup vs baseline: 1.5234x; 1.1983x over previous
//
#include <hip/hip_runtime.h>

// GCN_72971494359045: 2-layer GCNConv(+self-loops, sym-norm) with PReLU.
// N=50000 nodes, E=800000 edges, dims 128(+8 id)->256->128, all fp32.
//
// R4: (1) fill_csr atomicAdd(Ssum) removed (was 51 MB of scattered HBM RMW);
//     Svec computed by a post-CSR gather kernel instead.
//     (2) GEMMs moved to split-bf16 MFMA (a=hi+lo, 3-term product) --
//     fp32-equivalent precision at MFMA rate; B pre-packed in fragment
//     order; A frags held in registers (K<=256); no LDS, no barriers.

constexpr int NN = 50000;
constexpr int NE = 800000;
constexpr int SCAN_CHUNK = 1024;
constexpr int SCAN_NBLK = (NN + SCAN_CHUNK - 1) / SCAN_CHUNK;  // 49

typedef __attribute__((ext_vector_type(8))) short short8;
typedef __attribute__((ext_vector_type(4))) float floatx4;

__device__ inline void bsplit(float v, unsigned short& hi, unsigned short& lo) {
  unsigned u = __float_as_uint(v);
  hi = (unsigned short)(u >> 16);
  float rem = v - __uint_as_float(u & 0xffff0000u);
  lo = (unsigned short)(__float_as_uint(rem) >> 16);
}

__global__ void zero_int_kernel(int* __restrict__ p, int n) {
  int i = blockIdx.x * blockDim.x + threadIdx.x;
  if (i < n) p[i] = 0;
}

__global__ void count_deg_kernel(const int* __restrict__ ei, int* __restrict__ cnt) {
  int e = blockIdx.x * blockDim.x + threadIdx.x;
  if (e < NE) atomicAdd(&cnt[ei[NE + e]], 1);
}

__global__ void dinv_kernel(const int* __restrict__ cnt, float* __restrict__ dinv) {
  int i = blockIdx.x * blockDim.x + threadIdx.x;
  if (i < NN) dinv[i] = rsqrtf((float)(cnt[i] + 1));  // +1 self-loop
}

// --- hierarchical scan ---
__global__ void blocksum_kernel(const int* __restrict__ cnt, int* __restrict__ bsum) {
  __shared__ int sm[256];
  int b = blockIdx.x, t = threadIdx.x;
  int base = b * SCAN_CHUNK + t * 4;
  int s = 0;
#pragma unroll
  for (int j = 0; j < 4; ++j) {
    int i = base + j;
    if (i < NN) s += cnt[i];
  }
  sm[t] = s;
  __syncthreads();
  for (int off = 128; off > 0; off >>= 1) {
    if (t < off) sm[t] += sm[t + off];
    __syncthreads();
  }
  if (t == 0) bsum[b] = sm[0];
}

__global__ void scan_bsum_kernel(const int* __restrict__ bsum, int* __restrict__ bbase) {
  int t = threadIdx.x;  // 64
  int v = (t < SCAN_NBLK) ? bsum[t] : 0;
  for (int d = 1; d < 64; d <<= 1) {
    int u = __shfl_up(v, d, 64);
    if (t >= d) v += u;
  }
  int ex = __shfl_up(v, 1, 64);
  if (t == 0) ex = 0;
  if (t < SCAN_NBLK) bbase[t] = ex;
}

__global__ void scan_final_kernel(const int* __restrict__ cnt, const int* __restrict__ bbase,
                                  int* __restrict__ offs, int* __restrict__ cursor) {
  __shared__ int sm[256];
  int b = blockIdx.x, t = threadIdx.x;
  int base = b * SCAN_CHUNK + t * 4;
  int c[4];
  int s = 0;
#pragma unroll
  for (int j = 0; j < 4; ++j) {
    int i = base + j;
    c[j] = (i < NN) ? cnt[i] : 0;
    s += c[j];
  }
  sm[t] = s;
  __syncthreads();
  for (int off = 1; off < 256; off <<= 1) {
    int v = (t >= off) ? sm[t - off] : 0;
    __syncthreads();
    sm[t] += v;
    __syncthreads();
  }
  int run = bbase[b] + sm[t] - s;
#pragma unroll
  for (int j = 0; j < 4; ++j) {
    int i = base + j;
    if (i < NN) {
      offs[i] = run;
      cursor[i] = run;
      run += c[j];
    }
  }
  if (b == 0 && t == 0) offs[NN] = NE;
}

__global__ void fill_csr_kernel(const int* __restrict__ ei, int* __restrict__ cursor,
                                int* __restrict__ col) {
  int e = blockIdx.x * blockDim.x + threadIdx.x;
  if (e < NE) {
    int s = ei[e];
    int d = ei[NE + e];
    int pos = atomicAdd(&cursor[d], 1);
    col[pos] = s;
  }
}

// Svec[d] = dd*(dd + sum_{in-edges} dinv[s]) -- no atomics, dinv L2-resident.
__global__ void svec_kernel(const float* __restrict__ dinv, const int* __restrict__ offs,
                            const int* __restrict__ col, float* __restrict__ Svec) {
  int d = blockIdx.x * blockDim.x + threadIdx.x;
  if (d >= NN) return;
  float s = 0.f;
  int end = offs[d + 1];
  for (int p = offs[d]; p < end; ++p) s += dinv[col[p]];
  float dd = dinv[d];
  Svec[d] = dd * (dd + s);
}

__global__ void cvec_kernel(const float* __restrict__ idv, const float* __restrict__ W1,
                            float* __restrict__ cvec) {
  int m = threadIdx.x;  // 256
  float c = 0.f;
#pragma unroll
  for (int j = 0; j < 8; ++j) c += idv[j] * W1[(128 + j) * 256 + m];
  cvec[m] = c;
}

// xs[n,:] = x[n,:] * dinv[n]
__global__ void scale_x_kernel(const float* __restrict__ x, const float* __restrict__ dinv,
                               float* __restrict__ xs) {
  int i = blockIdx.x * blockDim.x + threadIdx.x;  // over NN*32 float4s
  if (i < NN * 32) {
    float dd = dinv[i >> 5];
    float4 v = ((const float4*)x)[i];
    v.x *= dd; v.y *= dd; v.z *= dd; v.w *= dd;
    ((float4*)xs)[i] = v;
  }
}

// Pack W[K x N] (fp32, row-major) into MFMA B-fragment order, split hi/lo:
// packed[((nt*KC + c)*64 + lane)*8 + j] = W[(c*32 + (lane>>4)*8 + j)*N + nt*16 + (lane&15)]
template <int K, int N>
__global__ void pack_b_kernel(const float* __restrict__ W, unsigned short* __restrict__ Bhi,
                              unsigned short* __restrict__ Blo) {
  int id = blockIdx.x * 256 + threadIdx.x;
  if (id >= K * N) return;
  constexpr int KC = K / 32;
  int j = id & 7;
  int lane = (id >> 3) & 63;
  int rest = id >> 9;
  int c = rest % KC;
  int nt = rest / KC;
  int k = c * 32 + (lane >> 4) * 8 + j;
  int n = nt * 16 + (lane & 15);
  unsigned short hi, lo;
  bsplit(W[(size_t)k * N + n], hi, lo);
  Bhi[id] = hi;
  Blo[id] = lo;
}

// Wave per node gather; 32 lanes x float4 cover the 128-wide row; two 32-lane
// halves take alternating edges, x2 unroll => 4 row-loads in flight/wave.
// MODE 0 (layer1): out = dd*(self+sum) -> split bf16 hi/lo.
// MODE 1 (layer2): out = prelu(dd*(self+sum)+b, a) -> fp32.
template <int MODE>
__global__ __launch_bounds__(256) void agg_kernel(
    const float* __restrict__ in, const float* __restrict__ dinv,
    const int* __restrict__ offs, const int* __restrict__ col,
    const float* __restrict__ bias, const float* __restrict__ alpha,
    unsigned short* __restrict__ outhi, unsigned short* __restrict__ outlo,
    float* __restrict__ outf) {
  const float4* in4 = (const float4*)in;
  int t = threadIdx.x;
  int node = blockIdx.x * 4 + (t >> 6);
  int lane = t & 63;
  int r = lane & 31;
  int half = lane >> 5;
  int beg = offs[node], end = offs[node + 1];

  float4 a0 = make_float4(0.f, 0.f, 0.f, 0.f);
  float4 a1 = make_float4(0.f, 0.f, 0.f, 0.f);
  int p = beg + half;
  for (; p + 2 < end; p += 4) {
    int s0 = col[p];
    int s1 = col[p + 2];
    float4 v0 = in4[(size_t)s0 * 32 + r];
    float4 v1 = in4[(size_t)s1 * 32 + r];
    a0.x += v0.x; a0.y += v0.y; a0.z += v0.z; a0.w += v0.w;
    a1.x += v1.x; a1.y += v1.y; a1.z += v1.z; a1.w += v1.w;
  }
  if (p < end) {
    float4 v0 = in4[(size_t)col[p] * 32 + r];
    a0.x += v0.x; a0.y += v0.y; a0.z += v0.z; a0.w += v0.w;
  }
  float4 acc = make_float4(a0.x + a1.x, a0.y + a1.y, a0.z + a1.z, a0.w + a1.w);
  acc.x += __shfl_xor(acc.x, 32);
  acc.y += __shfl_xor(acc.y, 32);
  acc.z += __shfl_xor(acc.z, 32);
  acc.w += __shfl_xor(acc.w, 32);

  float dd = dinv[node];
  if (half == 0) {
    float4 self = in4[(size_t)node * 32 + r];
    acc.x = dd * (acc.x + self.x);
    acc.y = dd * (acc.y + self.y);
    acc.z = dd * (acc.z + self.z);
    acc.w = dd * (acc.w + self.w);
    if (MODE == 0) {
      ushort4 h4, l4;
      bsplit(acc.x, h4.x, l4.x);
      bsplit(acc.y, h4.y, l4.y);
      bsplit(acc.z, h4.z, l4.z);
      bsplit(acc.w, h4.w, l4.w);
      ((ushort4*)outhi)[(size_t)node * 32 + r] = h4;
      ((ushort4*)outlo)[(size_t)node * 32 + r] = l4;
    } else {
      float4 b = ((const float4*)bias)[r];
      float4 al = ((const float4*)alpha)[r];
      acc.x += b.x; acc.y += b.y; acc.z += b.z; acc.w += b.w;
      acc.x = (acc.x >= 0.f) ? acc.x : al.x * acc.x;
      acc.y = (acc.y >= 0.f) ? acc.y : al.y * acc.y;
      acc.z = (acc.z >= 0.f) ? acc.z : al.z * acc.z;
      acc.w = (acc.w >= 0.f) ? acc.w : al.w * acc.w;
      ((float4*)outf)[(size_t)node * 32 + r] = acc;
    }
  }
}

// Split-bf16 MFMA GEMM: C[M,N] = (Ahi+Alo)[M,K] @ (Bhi+Blo)[K,N], 3-term.
// Wave = 16 rows x full N; A frags resident in regs; B read packed (L2-hot).
// MODE 1: v = prelu(acc + Svec[r]*cvec[c] + bias[c], alpha[c]) -> Chi/Clo bf16.
// MODE 2: v = acc * rowscale[r] -> Cf fp32.
template <int K, int N, int MODE>
__global__ __launch_bounds__(256) void gemm_mfma_kernel(
    const unsigned short* __restrict__ Ahi, const unsigned short* __restrict__ Alo,
    const unsigned short* __restrict__ Bhi, const unsigned short* __restrict__ Blo,
    const float* __restrict__ Svec, const float* __restrict__ cvec,
    const float* __restrict__ bias, const float* __restrict__ alpha,
    const float* __restrict__ rowscale,
    unsigned short* __restrict__ Chi, unsigned short* __restrict__ Clo,
    float* __restrict__ Cf) {
  constexpr int KC = K / 32;
  constexpr int NT = N / 16;
  int wave = threadIdx.x >> 6;
  int lane = threadIdx.x & 63;
  int row0 = blockIdx.x * 64 + wave * 16;
  if (row0 >= NN) return;  // NN % 16 == 0: whole wave in/out
  int m = lane & 15, quad = lane >> 4;
  int arow = row0 + m;

  short8 ah[KC], al[KC];
  const unsigned short* ap = Ahi + (size_t)arow * K + quad * 8;
  const unsigned short* alp = Alo + (size_t)arow * K + quad * 8;
#pragma unroll
  for (int c = 0; c < KC; ++c) {
    ah[c] = *(const short8*)(ap + c * 32);
    al[c] = *(const short8*)(alp + c * 32);
  }

  float sv[4];
#pragma unroll
  for (int i = 0; i < 4; ++i) {
    int r = row0 + quad * 4 + i;
    sv[i] = (MODE == 1) ? Svec[r] : rowscale[r];
  }

#pragma unroll 1
  for (int nt = 0; nt < NT; ++nt) {
    floatx4 acc = {0.f, 0.f, 0.f, 0.f};
#pragma unroll
    for (int c = 0; c < KC; ++c) {
      short8 bh = *(const short8*)(Bhi + ((size_t)(nt * KC + c) * 64 + lane) * 8);
      short8 bl = *(const short8*)(Blo + ((size_t)(nt * KC + c) * 64 + lane) * 8);
      acc = __builtin_amdgcn_mfma_f32_16x16x32_bf16(ah[c], bh, acc, 0, 0, 0);
      acc = __builtin_amdgcn_mfma_f32_16x16x32_bf16(ah[c], bl, acc, 0, 0, 0);
      acc = __builtin_amdgcn_mfma_f32_16x16x32_bf16(al[c], bh, acc, 0, 0, 0);
    }
    int c0 = nt * 16 + m;
    if (MODE == 1) {
      float cv = cvec[c0], bb = bias[c0], aa = alpha[c0];
#pragma unroll
      for (int i = 0; i < 4; ++i) {
        int r = row0 + quad * 4 + i;
        float v = acc[i] + sv[i] * cv + bb;
        v = (v >= 0.f) ? v : aa * v;
        unsigned short hi, lo;
        bsplit(v, hi, lo);
        Chi[(size_t)r * N + c0] = hi;
        Clo[(size_t)r * N + c0] = lo;
      }
    } else {
#pragma unroll
      for (int i = 0; i < 4; ++i) {
        int r = row0 + quad * 4 + i;
        Cf[(size_t)r * N + c0] = acc[i] * sv[i];
      }
    }
  }
}

extern "C" void kernel_launch(void* const* d_in, const int* in_sizes, int n_in,
                              void* d_out, int out_size, void* d_ws, size_t ws_size,
                              hipStream_t stream) {
  const float* x = (const float*)d_in[0];
  const int* ei = (const int*)d_in[1];
  const float* idv = (const float*)d_in[2];
  const float* W1 = (const float*)d_in[3];
  const float* b1 = (const float*)d_in[4];
  const float* a1 = (const float*)d_in[5];
  const float* W2 = (const float*)d_in[6];
  const float* b2 = (const float*)d_in[7];
  const float* a2 = (const float*)d_in[8];
  float* out = (float*)d_out;

  char* w = (char*)d_ws;
  size_t off = 0;
  auto alloc = [&](size_t bytes) -> void* {
    void* p = w + off;
    off += bytes;
    off = (off + 255) & ~(size_t)255;
    return p;
  };
  int* degcnt = (int*)alloc((size_t)NN * 4);
  float* dinv = (float*)alloc((size_t)NN * 4);
  float* Svec = (float*)alloc((size_t)NN * 4);
  int* offs = (int*)alloc((size_t)(NN + 1) * 4);
  int* cursor = (int*)alloc((size_t)NN * 4);
  int* col = (int*)alloc((size_t)NE * 4);
  float* cvec = (float*)alloc(256 * 4);
  int* bsum = (int*)alloc((size_t)SCAN_NBLK * 4);
  int* bbase = (int*)alloc((size_t)SCAN_NBLK * 4);
  float* xs = (float*)alloc((size_t)NN * 128 * 4);
  unsigned short* aggxhi = (unsigned short*)alloc((size_t)NN * 128 * 2);
  unsigned short* aggxlo = (unsigned short*)alloc((size_t)NN * 128 * 2);
  unsigned short* h1hi = (unsigned short*)alloc((size_t)NN * 256 * 2);
  unsigned short* h1lo = (unsigned short*)alloc((size_t)NN * 256 * 2);
  float* h2s = (float*)alloc((size_t)NN * 128 * 4);
  unsigned short* B1hi = (unsigned short*)alloc(128 * 256 * 2);
  unsigned short* B1lo = (unsigned short*)alloc(128 * 256 * 2);
  unsigned short* B2hi = (unsigned short*)alloc(256 * 128 * 2);
  unsigned short* B2lo = (unsigned short*)alloc(256 * 128 * 2);

  zero_int_kernel<<<(NN + 255) / 256, 256, 0, stream>>>(degcnt, NN);
  count_deg_kernel<<<(NE + 255) / 256, 256, 0, stream>>>(ei, degcnt);
  dinv_kernel<<<(NN + 255) / 256, 256, 0, stream>>>(degcnt, dinv);
  blocksum_kernel<<<SCAN_NBLK, 256, 0, stream>>>(degcnt, bsum);
  scan_bsum_kernel<<<1, 64, 0, stream>>>(bsum, bbase);
  scan_final_kernel<<<SCAN_NBLK, 256, 0, stream>>>(degcnt, bbase, offs, cursor);
  fill_csr_kernel<<<(NE + 255) / 256, 256, 0, stream>>>(ei, cursor, col);
  svec_kernel<<<(NN + 255) / 256, 256, 0, stream>>>(dinv, offs, col, Svec);
  cvec_kernel<<<1, 256, 0, stream>>>(idv, W1, cvec);
  scale_x_kernel<<<(NN * 32 + 255) / 256, 256, 0, stream>>>(x, dinv, xs);
  pack_b_kernel<128, 256><<<(128 * 256 + 255) / 256, 256, 0, stream>>>(W1, B1hi, B1lo);
  pack_b_kernel<256, 128><<<(256 * 128 + 255) / 256, 256, 0, stream>>>(W2, B2hi, B2lo);

  // layer-1 aggregate -> bf16 hi/lo
  agg_kernel<0><<<NN / 4, 256, 0, stream>>>(xs, dinv, offs, col, nullptr, nullptr,
                                            aggxhi, aggxlo, nullptr);

  // h1 = prelu(aggx@W1 + Svec*cvec + b1) -> bf16 hi/lo
  gemm_mfma_kernel<128, 256, 1><<<(NN + 63) / 64, 256, 0, stream>>>(
      aggxhi, aggxlo, B1hi, B1lo, Svec, cvec, b1, a1, nullptr, h1hi, h1lo, nullptr);

  // h2s = (h1@W2) * dinv[row] -> fp32
  gemm_mfma_kernel<256, 128, 2><<<(NN + 63) / 64, 256, 0, stream>>>(
      h1hi, h1lo, B2hi, B2lo, nullptr, nullptr, nullptr, nullptr, dinv,
      nullptr, nullptr, h2s);

  // layer-2 aggregate + bias + prelu
  agg_kernel<1><<<NN / 4, 256, 0, stream>>>(h2s, dinv, offs, col, b2, a2,
                                            nullptr, nullptr, out);
}

// Round 6
// 344.428 us; speedup vs baseline: 1.6680x; 1.0949x over previous
//
#include <hip/hip_runtime.h>

// GCN_72971494359045: 2-layer GCNConv(+self-loops, sym-norm) with PReLU.
// N=50000 nodes, E=800000 edges, dims 128(+8 id)->256->128, all fp32.
//
// R5: gathers read bf16 rows (256 B vs 512 B) -- halves the dominant edge
// traffic; accumulation stays fp32, GEMMs stay split-bf16 (3-term), so
// the only new error is one RTNE quantization of xs / h2s (~1e-3 at out).
// agg unrolled to 8 row-loads in flight/wave; fill_csr uses nontemporal
// stores for the scattered col writes.

constexpr int NN = 50000;
constexpr int NE = 800000;
constexpr int SCAN_CHUNK = 1024;
constexpr int SCAN_NBLK = (NN + SCAN_CHUNK - 1) / SCAN_CHUNK;  // 49

typedef __attribute__((ext_vector_type(8))) short short8;
typedef __attribute__((ext_vector_type(4))) float floatx4;

__device__ inline void bsplit(float v, unsigned short& hi, unsigned short& lo) {
  unsigned u = __float_as_uint(v);
  hi = (unsigned short)(u >> 16);
  float rem = v - __uint_as_float(u & 0xffff0000u);
  lo = (unsigned short)(__float_as_uint(rem) >> 16);
}

__device__ inline unsigned short bf16_rtne(float v) {
  unsigned u = __float_as_uint(v);
  return (unsigned short)((u + 0x7fffu + ((u >> 16) & 1u)) >> 16);
}

__device__ inline float bflo(unsigned u) { return __uint_as_float(u << 16); }
__device__ inline float bfhi(unsigned u) { return __uint_as_float(u & 0xffff0000u); }

__global__ void zero_int_kernel(int* __restrict__ p, int n) {
  int i = blockIdx.x * blockDim.x + threadIdx.x;
  if (i < n) p[i] = 0;
}

__global__ void count_deg_kernel(const int* __restrict__ ei, int* __restrict__ cnt) {
  int e = blockIdx.x * blockDim.x + threadIdx.x;
  if (e < NE) atomicAdd(&cnt[ei[NE + e]], 1);
}

__global__ void dinv_kernel(const int* __restrict__ cnt, float* __restrict__ dinv) {
  int i = blockIdx.x * blockDim.x + threadIdx.x;
  if (i < NN) dinv[i] = rsqrtf((float)(cnt[i] + 1));  // +1 self-loop
}

// --- hierarchical scan ---
__global__ void blocksum_kernel(const int* __restrict__ cnt, int* __restrict__ bsum) {
  __shared__ int sm[256];
  int b = blockIdx.x, t = threadIdx.x;
  int base = b * SCAN_CHUNK + t * 4;
  int s = 0;
#pragma unroll
  for (int j = 0; j < 4; ++j) {
    int i = base + j;
    if (i < NN) s += cnt[i];
  }
  sm[t] = s;
  __syncthreads();
  for (int off = 128; off > 0; off >>= 1) {
    if (t < off) sm[t] += sm[t + off];
    __syncthreads();
  }
  if (t == 0) bsum[b] = sm[0];
}

__global__ void scan_bsum_kernel(const int* __restrict__ bsum, int* __restrict__ bbase) {
  int t = threadIdx.x;  // 64
  int v = (t < SCAN_NBLK) ? bsum[t] : 0;
  for (int d = 1; d < 64; d <<= 1) {
    int u = __shfl_up(v, d, 64);
    if (t >= d) v += u;
  }
  int ex = __shfl_up(v, 1, 64);
  if (t == 0) ex = 0;
  if (t < SCAN_NBLK) bbase[t] = ex;
}

__global__ void scan_final_kernel(const int* __restrict__ cnt, const int* __restrict__ bbase,
                                  int* __restrict__ offs, int* __restrict__ cursor) {
  __shared__ int sm[256];
  int b = blockIdx.x, t = threadIdx.x;
  int base = b * SCAN_CHUNK + t * 4;
  int c[4];
  int s = 0;
#pragma unroll
  for (int j = 0; j < 4; ++j) {
    int i = base + j;
    c[j] = (i < NN) ? cnt[i] : 0;
    s += c[j];
  }
  sm[t] = s;
  __syncthreads();
  for (int off = 1; off < 256; off <<= 1) {
    int v = (t >= off) ? sm[t - off] : 0;
    __syncthreads();
    sm[t] += v;
    __syncthreads();
  }
  int run = bbase[b] + sm[t] - s;
#pragma unroll
  for (int j = 0; j < 4; ++j) {
    int i = base + j;
    if (i < NN) {
      offs[i] = run;
      cursor[i] = run;
      run += c[j];
    }
  }
  if (b == 0 && t == 0) offs[NN] = NE;
}

__global__ void fill_csr_kernel(const int* __restrict__ ei, int* __restrict__ cursor,
                                int* __restrict__ col) {
  int e = blockIdx.x * blockDim.x + threadIdx.x;
  if (e < NE) {
    int s = ei[e];
    int d = ei[NE + e];
    int pos = atomicAdd(&cursor[d], 1);
    __builtin_nontemporal_store(s, &col[pos]);
  }
}

// Svec[d] = dd*(dd + sum_{in-edges} dinv[s]) -- no atomics, dinv L2-resident.
__global__ void svec_kernel(const float* __restrict__ dinv, const int* __restrict__ offs,
                            const int* __restrict__ col, float* __restrict__ Svec) {
  int d = blockIdx.x * blockDim.x + threadIdx.x;
  if (d >= NN) return;
  float s = 0.f;
  int end = offs[d + 1];
  for (int p = offs[d]; p < end; ++p) s += dinv[col[p]];
  float dd = dinv[d];
  Svec[d] = dd * (dd + s);
}

__global__ void cvec_kernel(const float* __restrict__ idv, const float* __restrict__ W1,
                            float* __restrict__ cvec) {
  int m = threadIdx.x;  // 256
  float c = 0.f;
#pragma unroll
  for (int j = 0; j < 8; ++j) c += idv[j] * W1[(128 + j) * 256 + m];
  cvec[m] = c;
}

// xsb[n,:] = bf16(x[n,:] * dinv[n])
__global__ void scale_x_kernel(const float* __restrict__ x, const float* __restrict__ dinv,
                               unsigned short* __restrict__ xsb) {
  int i = blockIdx.x * blockDim.x + threadIdx.x;  // over NN*32 float4s
  if (i < NN * 32) {
    float dd = dinv[i >> 5];
    float4 v = ((const float4*)x)[i];
    ushort4 o;
    o.x = bf16_rtne(v.x * dd);
    o.y = bf16_rtne(v.y * dd);
    o.z = bf16_rtne(v.z * dd);
    o.w = bf16_rtne(v.w * dd);
    ((ushort4*)xsb)[i] = o;
  }
}

// Pack W[K x N] (fp32, row-major) into MFMA B-fragment order, split hi/lo.
template <int K, int N>
__global__ void pack_b_kernel(const float* __restrict__ W, unsigned short* __restrict__ Bhi,
                              unsigned short* __restrict__ Blo) {
  int id = blockIdx.x * 256 + threadIdx.x;
  if (id >= K * N) return;
  constexpr int KC = K / 32;
  int j = id & 7;
  int lane = (id >> 3) & 63;
  int rest = id >> 9;
  int c = rest % KC;
  int nt = rest / KC;
  int k = c * 32 + (lane >> 4) * 8 + j;
  int n = nt * 16 + (lane & 15);
  unsigned short hi, lo;
  bsplit(W[(size_t)k * N + n], hi, lo);
  Bhi[id] = hi;
  Blo[id] = lo;
}

// Wave per node; 32 lanes x 4 bf16 (uint2) cover the 128-wide row; two
// 32-lane halves take alternating edges, x4 unroll => 8 row-loads in flight.
// MODE 0 (layer1): out = dd*(self+sum) -> split bf16 hi/lo (for GEMM A).
// MODE 1 (layer2): out = prelu(dd*(self+sum)+b, a) -> fp32 final output.
template <int MODE>
__global__ __launch_bounds__(256) void agg_kernel(
    const unsigned short* __restrict__ in, const float* __restrict__ dinv,
    const int* __restrict__ offs, const int* __restrict__ col,
    const float* __restrict__ bias, const float* __restrict__ alpha,
    unsigned short* __restrict__ outhi, unsigned short* __restrict__ outlo,
    float* __restrict__ outf) {
  const uint2* inb = (const uint2*)in;  // row = 32 uint2 (128 bf16)
  int t = threadIdx.x;
  int node = blockIdx.x * 4 + (t >> 6);
  int lane = t & 63;
  int r = lane & 31;
  int half = lane >> 5;
  int beg = offs[node], end = offs[node + 1];

  float4 a0 = make_float4(0.f, 0.f, 0.f, 0.f);
  float4 a1 = make_float4(0.f, 0.f, 0.f, 0.f);
  int p = beg + half;
  for (; p + 6 < end; p += 8) {
    int s0 = col[p];
    int s1 = col[p + 2];
    int s2 = col[p + 4];
    int s3 = col[p + 6];
    uint2 v0 = inb[(size_t)s0 * 32 + r];
    uint2 v1 = inb[(size_t)s1 * 32 + r];
    uint2 v2 = inb[(size_t)s2 * 32 + r];
    uint2 v3 = inb[(size_t)s3 * 32 + r];
    a0.x += bflo(v0.x); a0.y += bfhi(v0.x); a0.z += bflo(v0.y); a0.w += bfhi(v0.y);
    a1.x += bflo(v1.x); a1.y += bfhi(v1.x); a1.z += bflo(v1.y); a1.w += bfhi(v1.y);
    a0.x += bflo(v2.x); a0.y += bfhi(v2.x); a0.z += bflo(v2.y); a0.w += bfhi(v2.y);
    a1.x += bflo(v3.x); a1.y += bfhi(v3.x); a1.z += bflo(v3.y); a1.w += bfhi(v3.y);
  }
  for (; p < end; p += 2) {
    uint2 v0 = inb[(size_t)col[p] * 32 + r];
    a0.x += bflo(v0.x); a0.y += bfhi(v0.x); a0.z += bflo(v0.y); a0.w += bfhi(v0.y);
  }
  float4 acc = make_float4(a0.x + a1.x, a0.y + a1.y, a0.z + a1.z, a0.w + a1.w);
  acc.x += __shfl_xor(acc.x, 32);
  acc.y += __shfl_xor(acc.y, 32);
  acc.z += __shfl_xor(acc.z, 32);
  acc.w += __shfl_xor(acc.w, 32);

  float dd = dinv[node];
  if (half == 0) {
    uint2 sv = inb[(size_t)node * 32 + r];
    acc.x = dd * (acc.x + bflo(sv.x));
    acc.y = dd * (acc.y + bfhi(sv.x));
    acc.z = dd * (acc.z + bflo(sv.y));
    acc.w = dd * (acc.w + bfhi(sv.y));
    if (MODE == 0) {
      ushort4 h4, l4;
      bsplit(acc.x, h4.x, l4.x);
      bsplit(acc.y, h4.y, l4.y);
      bsplit(acc.z, h4.z, l4.z);
      bsplit(acc.w, h4.w, l4.w);
      ((ushort4*)outhi)[(size_t)node * 32 + r] = h4;
      ((ushort4*)outlo)[(size_t)node * 32 + r] = l4;
    } else {
      float4 b = ((const float4*)bias)[r];
      float4 al = ((const float4*)alpha)[r];
      acc.x += b.x; acc.y += b.y; acc.z += b.z; acc.w += b.w;
      acc.x = (acc.x >= 0.f) ? acc.x : al.x * acc.x;
      acc.y = (acc.y >= 0.f) ? acc.y : al.y * acc.y;
      acc.z = (acc.z >= 0.f) ? acc.z : al.z * acc.z;
      acc.w = (acc.w >= 0.f) ? acc.w : al.w * acc.w;
      ((float4*)outf)[(size_t)node * 32 + r] = acc;
    }
  }
}

// Split-bf16 MFMA GEMM: C[M,N] = (Ahi+Alo)[M,K] @ (Bhi+Blo)[K,N], 3-term.
// Wave = 16 rows x full N; A frags resident in regs; B read packed (L2-hot).
// MODE 1: v = prelu(acc + Svec[r]*cvec[c] + bias[c], alpha[c]) -> Chi/Clo bf16.
// MODE 2: v = acc * rowscale[r] -> Cb bf16 (feeds the layer-2 gather).
template <int K, int N, int MODE>
__global__ __launch_bounds__(256) void gemm_mfma_kernel(
    const unsigned short* __restrict__ Ahi, const unsigned short* __restrict__ Alo,
    const unsigned short* __restrict__ Bhi, const unsigned short* __restrict__ Blo,
    const float* __restrict__ Svec, const float* __restrict__ cvec,
    const float* __restrict__ bias, const float* __restrict__ alpha,
    const float* __restrict__ rowscale,
    unsigned short* __restrict__ Chi, unsigned short* __restrict__ Clo,
    unsigned short* __restrict__ Cb) {
  constexpr int KC = K / 32;
  constexpr int NT = N / 16;
  int wave = threadIdx.x >> 6;
  int lane = threadIdx.x & 63;
  int row0 = blockIdx.x * 64 + wave * 16;
  if (row0 >= NN) return;  // NN % 16 == 0: whole wave in/out
  int m = lane & 15, quad = lane >> 4;
  int arow = row0 + m;

  short8 ah[KC], al[KC];
  const unsigned short* ap = Ahi + (size_t)arow * K + quad * 8;
  const unsigned short* alp = Alo + (size_t)arow * K + quad * 8;
#pragma unroll
  for (int c = 0; c < KC; ++c) {
    ah[c] = *(const short8*)(ap + c * 32);
    al[c] = *(const short8*)(alp + c * 32);
  }

  float sv[4];
#pragma unroll
  for (int i = 0; i < 4; ++i) {
    int r = row0 + quad * 4 + i;
    sv[i] = (MODE == 1) ? Svec[r] : rowscale[r];
  }

#pragma unroll 1
  for (int nt = 0; nt < NT; ++nt) {
    floatx4 acc = {0.f, 0.f, 0.f, 0.f};
#pragma unroll
    for (int c = 0; c < KC; ++c) {
      short8 bh = *(const short8*)(Bhi + ((size_t)(nt * KC + c) * 64 + lane) * 8);
      short8 bl = *(const short8*)(Blo + ((size_t)(nt * KC + c) * 64 + lane) * 8);
      acc = __builtin_amdgcn_mfma_f32_16x16x32_bf16(ah[c], bh, acc, 0, 0, 0);
      acc = __builtin_amdgcn_mfma_f32_16x16x32_bf16(ah[c], bl, acc, 0, 0, 0);
      acc = __builtin_amdgcn_mfma_f32_16x16x32_bf16(al[c], bh, acc, 0, 0, 0);
    }
    int c0 = nt * 16 + m;
    if (MODE == 1) {
      float cv = cvec[c0], bb = bias[c0], aa = alpha[c0];
#pragma unroll
      for (int i = 0; i < 4; ++i) {
        int r = row0 + quad * 4 + i;
        float v = acc[i] + sv[i] * cv + bb;
        v = (v >= 0.f) ? v : aa * v;
        unsigned short hi, lo;
        bsplit(v, hi, lo);
        Chi[(size_t)r * N + c0] = hi;
        Clo[(size_t)r * N + c0] = lo;
      }
    } else {
#pragma unroll
      for (int i = 0; i < 4; ++i) {
        int r = row0 + quad * 4 + i;
        Cb[(size_t)r * N + c0] = bf16_rtne(acc[i] * sv[i]);
      }
    }
  }
}

extern "C" void kernel_launch(void* const* d_in, const int* in_sizes, int n_in,
                              void* d_out, int out_size, void* d_ws, size_t ws_size,
                              hipStream_t stream) {
  const float* x = (const float*)d_in[0];
  const int* ei = (const int*)d_in[1];
  const float* idv = (const float*)d_in[2];
  const float* W1 = (const float*)d_in[3];
  const float* b1 = (const float*)d_in[4];
  const float* a1 = (const float*)d_in[5];
  const float* W2 = (const float*)d_in[6];
  const float* b2 = (const float*)d_in[7];
  const float* a2 = (const float*)d_in[8];
  float* out = (float*)d_out;

  char* w = (char*)d_ws;
  size_t off = 0;
  auto alloc = [&](size_t bytes) -> void* {
    void* p = w + off;
    off += bytes;
    off = (off + 255) & ~(size_t)255;
    return p;
  };
  int* degcnt = (int*)alloc((size_t)NN * 4);
  float* dinv = (float*)alloc((size_t)NN * 4);
  float* Svec = (float*)alloc((size_t)NN * 4);
  int* offs = (int*)alloc((size_t)(NN + 1) * 4);
  int* cursor = (int*)alloc((size_t)NN * 4);
  int* col = (int*)alloc((size_t)NE * 4);
  float* cvec = (float*)alloc(256 * 4);
  int* bsum = (int*)alloc((size_t)SCAN_NBLK * 4);
  int* bbase = (int*)alloc((size_t)SCAN_NBLK * 4);
  unsigned short* xsb = (unsigned short*)alloc((size_t)NN * 128 * 2);
  unsigned short* aggxhi = (unsigned short*)alloc((size_t)NN * 128 * 2);
  unsigned short* aggxlo = (unsigned short*)alloc((size_t)NN * 128 * 2);
  unsigned short* h1hi = (unsigned short*)alloc((size_t)NN * 256 * 2);
  unsigned short* h1lo = (unsigned short*)alloc((size_t)NN * 256 * 2);
  unsigned short* h2b = (unsigned short*)alloc((size_t)NN * 128 * 2);
  unsigned short* B1hi = (unsigned short*)alloc(128 * 256 * 2);
  unsigned short* B1lo = (unsigned short*)alloc(128 * 256 * 2);
  unsigned short* B2hi = (unsigned short*)alloc(256 * 128 * 2);
  unsigned short* B2lo = (unsigned short*)alloc(256 * 128 * 2);

  zero_int_kernel<<<(NN + 255) / 256, 256, 0, stream>>>(degcnt, NN);
  count_deg_kernel<<<(NE + 255) / 256, 256, 0, stream>>>(ei, degcnt);
  dinv_kernel<<<(NN + 255) / 256, 256, 0, stream>>>(degcnt, dinv);
  blocksum_kernel<<<SCAN_NBLK, 256, 0, stream>>>(degcnt, bsum);
  scan_bsum_kernel<<<1, 64, 0, stream>>>(bsum, bbase);
  scan_final_kernel<<<SCAN_NBLK, 256, 0, stream>>>(degcnt, bbase, offs, cursor);
  fill_csr_kernel<<<(NE + 255) / 256, 256, 0, stream>>>(ei, cursor, col);
  svec_kernel<<<(NN + 255) / 256, 256, 0, stream>>>(dinv, offs, col, Svec);
  cvec_kernel<<<1, 256, 0, stream>>>(idv, W1, cvec);
  scale_x_kernel<<<(NN * 32 + 255) / 256, 256, 0, stream>>>(x, dinv, xsb);
  pack_b_kernel<128, 256><<<(128 * 256 + 255) / 256, 256, 0, stream>>>(W1, B1hi, B1lo);
  pack_b_kernel<256, 128><<<(256 * 128 + 255) / 256, 256, 0, stream>>>(W2, B2hi, B2lo);

  // layer-1 aggregate (bf16 gather, fp32 accum) -> split bf16 hi/lo
  agg_kernel<0><<<NN / 4, 256, 0, stream>>>(xsb, dinv, offs, col, nullptr, nullptr,
                                            aggxhi, aggxlo, nullptr);

  // h1 = prelu(aggx@W1 + Svec*cvec + b1) -> bf16 hi/lo
  gemm_mfma_kernel<128, 256, 1><<<(NN + 63) / 64, 256, 0, stream>>>(
      aggxhi, aggxlo, B1hi, B1lo, Svec, cvec, b1, a1, nullptr, h1hi, h1lo, nullptr);

  // h2b = bf16((h1@W2) * dinv[row])
  gemm_mfma_kernel<256, 128, 2><<<(NN + 63) / 64, 256, 0, stream>>>(
      h1hi, h1lo, B2hi, B2lo, nullptr, nullptr, nullptr, nullptr, dinv,
      nullptr, nullptr, h2b);

  // layer-2 aggregate (bf16 gather) + bias + prelu -> fp32 out
  agg_kernel<1><<<NN / 4, 256, 0, stream>>>(h2b, dinv, offs, col, b2, a2,
                                            nullptr, nullptr, out);
}

// Round 7
// 309.997 us; speedup vs baseline: 1.8532x; 1.1111x over previous
//
#include <hip/hip_runtime.h>

// GCN_72971494359045: 2-layer GCNConv(+self-loops, sym-norm) with PReLU.
// N=50000 nodes, E=800000 edges, dims 128(+8 id)->256->128, all fp32.
//
// R6: CSR front-end rebuilt as a two-level binned radix partition
// (bucket = dst>>9, 98 buckets x 512 nodes). Kills the 60 MB of
// write-amplified random scatter (fill_csr) and the 800k scattered
// count_deg atomics; deg/offs/dinv all come out of the per-bucket pass.

constexpr int NN = 50000;
constexpr int NE = 800000;
constexpr int NBUCK = 98;     // ceil(NN / 512), bucket = dst >> 9
constexpr int TILE = 8192;    // edges per scatter block
constexpr int NSCAT = (NE + TILE - 1) / TILE;  // 98

typedef __attribute__((ext_vector_type(8))) short short8;
typedef __attribute__((ext_vector_type(4))) float floatx4;

__device__ inline void bsplit(float v, unsigned short& hi, unsigned short& lo) {
  unsigned u = __float_as_uint(v);
  hi = (unsigned short)(u >> 16);
  float rem = v - __uint_as_float(u & 0xffff0000u);
  lo = (unsigned short)(__float_as_uint(rem) >> 16);
}

__device__ inline unsigned short bf16_rtne(float v) {
  unsigned u = __float_as_uint(v);
  return (unsigned short)((u + 0x7fffu + ((u >> 16) & 1u)) >> 16);
}

__device__ inline float bflo(unsigned u) { return __uint_as_float(u << 16); }
__device__ inline float bfhi(unsigned u) { return __uint_as_float(u & 0xffff0000u); }

// --- binned CSR build ---

__global__ void zero_small_kernel(int* __restrict__ bcnt) {
  int t = threadIdx.x;
  if (t < NBUCK) bcnt[t] = 0;
}

__global__ __launch_bounds__(256) void bucket_count_kernel(const int* __restrict__ ei,
                                                           int* __restrict__ bcnt) {
  __shared__ int h[NBUCK];
  int t = threadIdx.x;
  for (int i = t; i < NBUCK; i += 256) h[i] = 0;
  __syncthreads();
  int base = blockIdx.x * TILE;
  int end = base + TILE; if (end > NE) end = NE;
  for (int e = base + t; e < end; e += 256) {
    int d = ei[NE + e];
    atomicAdd(&h[d >> 9], 1);
  }
  __syncthreads();
  for (int i = t; i < NBUCK; i += 256)
    if (h[i]) atomicAdd(&bcnt[i], h[i]);
}

__global__ void bucket_scan_kernel(const int* __restrict__ bcnt, int* __restrict__ bbase,
                                   int* __restrict__ bcur) {
  __shared__ int sm[128];
  int t = threadIdx.x;  // 128
  int v = (t < NBUCK) ? bcnt[t] : 0;
  sm[t] = v;
  __syncthreads();
  for (int off = 1; off < 128; off <<= 1) {
    int u = (t >= off) ? sm[t - off] : 0;
    __syncthreads();
    sm[t] += u;
    __syncthreads();
  }
  if (t < NBUCK) {
    bbase[t] = sm[t] - v;
    bcur[t] = sm[t] - v;
  }
}

// Radix partition: stage tile in LDS grouped by bucket, flush contiguous
// per-bucket chunks (coalesced) into ebuf. val = (dst&511)<<16 | src.
__global__ __launch_bounds__(256) void bucket_scatter_kernel(const int* __restrict__ ei,
                                                             int* __restrict__ bcur,
                                                             unsigned* __restrict__ ebuf) {
  __shared__ int h[NBUCK], lbase[NBUCK], gb[NBUCK], lcur[NBUCK];
  __shared__ int ssc[128];
  __shared__ unsigned stage[TILE];
  int t = threadIdx.x;
  for (int i = t; i < NBUCK; i += 256) h[i] = 0;
  __syncthreads();
  int base = blockIdx.x * TILE;
  int end = base + TILE; if (end > NE) end = NE;
  for (int e = base + t; e < end; e += 256) {
    int d = ei[NE + e];
    atomicAdd(&h[d >> 9], 1);
  }
  __syncthreads();
  if (t < 128) ssc[t] = (t < NBUCK) ? h[t] : 0;
  __syncthreads();
  for (int off = 1; off < 128; off <<= 1) {
    int u = 0;
    if (t < 128 && t >= off) u = ssc[t - off];
    __syncthreads();
    if (t < 128) ssc[t] += u;
    __syncthreads();
  }
  if (t < NBUCK) {
    int ex = ssc[t] - h[t];
    lbase[t] = ex;
    lcur[t] = ex;
    gb[t] = atomicAdd(&bcur[t], h[t]);
  }
  __syncthreads();
  for (int e = base + t; e < end; e += 256) {
    int s = ei[e];
    int d = ei[NE + e];
    int b = d >> 9;
    int pos = atomicAdd(&lcur[b], 1);
    stage[pos] = ((unsigned)(d & 511) << 16) | (unsigned)s;
  }
  __syncthreads();
  for (int b = 0; b < NBUCK; ++b) {
    int c = h[b], lb = lbase[b], g = gb[b];
    for (int i = t; i < c; i += 256) ebuf[g + i] = stage[lb + i];
  }
}

// One block per bucket: node histogram -> offs/dinv, then scatter col into
// the bucket's contiguous window (L2-resident, full-line evictions).
__global__ __launch_bounds__(256) void bucket_csr_kernel(
    const unsigned* __restrict__ ebuf, const int* __restrict__ bbase,
    const int* __restrict__ bcnt, int* __restrict__ offs, int* __restrict__ col,
    float* __restrict__ dinv) {
  __shared__ int cnt[512], cur[512], sums[256];
  int b = blockIdx.x, t = threadIdx.x;
  int node0 = b << 9;
  int nnode = NN - node0; if (nnode > 512) nnode = 512;
  for (int i = t; i < 512; i += 256) cnt[i] = 0;
  __syncthreads();
  int g0 = bbase[b], g1 = g0 + bcnt[b];
  for (int i = g0 + t; i < g1; i += 256) atomicAdd(&cnt[ebuf[i] >> 16], 1);
  __syncthreads();
  int c0 = cnt[2 * t], c1 = cnt[2 * t + 1];
  int s = c0 + c1;
  sums[t] = s;
  __syncthreads();
  for (int off = 1; off < 256; off <<= 1) {
    int u = (t >= off) ? sums[t - off] : 0;
    __syncthreads();
    sums[t] += u;
    __syncthreads();
  }
  int ex = sums[t] - s;
  cur[2 * t] = ex;
  cur[2 * t + 1] = ex + c0;
  if (2 * t < nnode) {
    offs[node0 + 2 * t] = g0 + ex;
    dinv[node0 + 2 * t] = rsqrtf((float)(c0 + 1));
  }
  if (2 * t + 1 < nnode) {
    offs[node0 + 2 * t + 1] = g0 + ex + c0;
    dinv[node0 + 2 * t + 1] = rsqrtf((float)(c1 + 1));
  }
  __syncthreads();
  for (int i = g0 + t; i < g1; i += 256) {
    unsigned v = ebuf[i];
    int dl = v >> 16;
    int pos = atomicAdd(&cur[dl], 1);
    col[g0 + pos] = (int)(v & 0xffffu);
  }
  if (b == 0 && t == 0) offs[NN] = NE;
}

// Svec[d] = dd*(dd + sum_{in-edges} dinv[s])
__global__ void svec_kernel(const float* __restrict__ dinv, const int* __restrict__ offs,
                            const int* __restrict__ col, float* __restrict__ Svec) {
  int d = blockIdx.x * blockDim.x + threadIdx.x;
  if (d >= NN) return;
  float s = 0.f;
  int end = offs[d + 1];
  for (int p = offs[d]; p < end; ++p) s += dinv[col[p]];
  float dd = dinv[d];
  Svec[d] = dd * (dd + s);
}

__global__ void cvec_kernel(const float* __restrict__ idv, const float* __restrict__ W1,
                            float* __restrict__ cvec) {
  int m = threadIdx.x;  // 256
  float c = 0.f;
#pragma unroll
  for (int j = 0; j < 8; ++j) c += idv[j] * W1[(128 + j) * 256 + m];
  cvec[m] = c;
}

// xsb[n,:] = bf16(x[n,:] * dinv[n])
__global__ void scale_x_kernel(const float* __restrict__ x, const float* __restrict__ dinv,
                               unsigned short* __restrict__ xsb) {
  int i = blockIdx.x * blockDim.x + threadIdx.x;  // over NN*32 float4s
  if (i < NN * 32) {
    float dd = dinv[i >> 5];
    float4 v = ((const float4*)x)[i];
    ushort4 o;
    o.x = bf16_rtne(v.x * dd);
    o.y = bf16_rtne(v.y * dd);
    o.z = bf16_rtne(v.z * dd);
    o.w = bf16_rtne(v.w * dd);
    ((ushort4*)xsb)[i] = o;
  }
}

// Pack W[K x N] (fp32, row-major) into MFMA B-fragment order, split hi/lo.
template <int K, int N>
__global__ void pack_b_kernel(const float* __restrict__ W, unsigned short* __restrict__ Bhi,
                              unsigned short* __restrict__ Blo) {
  int id = blockIdx.x * 256 + threadIdx.x;
  if (id >= K * N) return;
  constexpr int KC = K / 32;
  int j = id & 7;
  int lane = (id >> 3) & 63;
  int rest = id >> 9;
  int c = rest % KC;
  int nt = rest / KC;
  int k = c * 32 + (lane >> 4) * 8 + j;
  int n = nt * 16 + (lane & 15);
  unsigned short hi, lo;
  bsplit(W[(size_t)k * N + n], hi, lo);
  Bhi[id] = hi;
  Blo[id] = lo;
}

// Wave per node; 32 lanes x 4 bf16 (uint2) cover the 128-wide row; two
// 32-lane halves take alternating edges, x4 unroll => 8 row-loads in flight.
// MODE 0 (layer1): out = dd*(self+sum) -> split bf16 hi/lo (for GEMM A).
// MODE 1 (layer2): out = prelu(dd*(self+sum)+b, a) -> fp32 final output.
template <int MODE>
__global__ __launch_bounds__(256) void agg_kernel(
    const unsigned short* __restrict__ in, const float* __restrict__ dinv,
    const int* __restrict__ offs, const int* __restrict__ col,
    const float* __restrict__ bias, const float* __restrict__ alpha,
    unsigned short* __restrict__ outhi, unsigned short* __restrict__ outlo,
    float* __restrict__ outf) {
  const uint2* inb = (const uint2*)in;  // row = 32 uint2 (128 bf16)
  int t = threadIdx.x;
  int node = blockIdx.x * 4 + (t >> 6);
  int lane = t & 63;
  int r = lane & 31;
  int half = lane >> 5;
  int beg = offs[node], end = offs[node + 1];

  float4 a0 = make_float4(0.f, 0.f, 0.f, 0.f);
  float4 a1 = make_float4(0.f, 0.f, 0.f, 0.f);
  int p = beg + half;
  for (; p + 6 < end; p += 8) {
    int s0 = col[p];
    int s1 = col[p + 2];
    int s2 = col[p + 4];
    int s3 = col[p + 6];
    uint2 v0 = inb[(size_t)s0 * 32 + r];
    uint2 v1 = inb[(size_t)s1 * 32 + r];
    uint2 v2 = inb[(size_t)s2 * 32 + r];
    uint2 v3 = inb[(size_t)s3 * 32 + r];
    a0.x += bflo(v0.x); a0.y += bfhi(v0.x); a0.z += bflo(v0.y); a0.w += bfhi(v0.y);
    a1.x += bflo(v1.x); a1.y += bfhi(v1.x); a1.z += bflo(v1.y); a1.w += bfhi(v1.y);
    a0.x += bflo(v2.x); a0.y += bfhi(v2.x); a0.z += bflo(v2.y); a0.w += bfhi(v2.y);
    a1.x += bflo(v3.x); a1.y += bfhi(v3.x); a1.z += bflo(v3.y); a1.w += bfhi(v3.y);
  }
  for (; p < end; p += 2) {
    uint2 v0 = inb[(size_t)col[p] * 32 + r];
    a0.x += bflo(v0.x); a0.y += bfhi(v0.x); a0.z += bflo(v0.y); a0.w += bfhi(v0.y);
  }
  float4 acc = make_float4(a0.x + a1.x, a0.y + a1.y, a0.z + a1.z, a0.w + a1.w);
  acc.x += __shfl_xor(acc.x, 32);
  acc.y += __shfl_xor(acc.y, 32);
  acc.z += __shfl_xor(acc.z, 32);
  acc.w += __shfl_xor(acc.w, 32);

  float dd = dinv[node];
  if (half == 0) {
    uint2 sv = inb[(size_t)node * 32 + r];
    acc.x = dd * (acc.x + bflo(sv.x));
    acc.y = dd * (acc.y + bfhi(sv.x));
    acc.z = dd * (acc.z + bflo(sv.y));
    acc.w = dd * (acc.w + bfhi(sv.y));
    if (MODE == 0) {
      ushort4 h4, l4;
      bsplit(acc.x, h4.x, l4.x);
      bsplit(acc.y, h4.y, l4.y);
      bsplit(acc.z, h4.z, l4.z);
      bsplit(acc.w, h4.w, l4.w);
      ((ushort4*)outhi)[(size_t)node * 32 + r] = h4;
      ((ushort4*)outlo)[(size_t)node * 32 + r] = l4;
    } else {
      float4 b = ((const float4*)bias)[r];
      float4 al = ((const float4*)alpha)[r];
      acc.x += b.x; acc.y += b.y; acc.z += b.z; acc.w += b.w;
      acc.x = (acc.x >= 0.f) ? acc.x : al.x * acc.x;
      acc.y = (acc.y >= 0.f) ? acc.y : al.y * acc.y;
      acc.z = (acc.z >= 0.f) ? acc.z : al.z * acc.z;
      acc.w = (acc.w >= 0.f) ? acc.w : al.w * acc.w;
      ((float4*)outf)[(size_t)node * 32 + r] = acc;
    }
  }
}

// Split-bf16 MFMA GEMM: C[M,N] = (Ahi+Alo)[M,K] @ (Bhi+Blo)[K,N], 3-term.
// MODE 1: v = prelu(acc + Svec[r]*cvec[c] + bias[c], alpha[c]) -> Chi/Clo bf16.
// MODE 2: v = acc * rowscale[r] -> Cb bf16 (feeds the layer-2 gather).
template <int K, int N, int MODE>
__global__ __launch_bounds__(256) void gemm_mfma_kernel(
    const unsigned short* __restrict__ Ahi, const unsigned short* __restrict__ Alo,
    const unsigned short* __restrict__ Bhi, const unsigned short* __restrict__ Blo,
    const float* __restrict__ Svec, const float* __restrict__ cvec,
    const float* __restrict__ bias, const float* __restrict__ alpha,
    const float* __restrict__ rowscale,
    unsigned short* __restrict__ Chi, unsigned short* __restrict__ Clo,
    unsigned short* __restrict__ Cb) {
  constexpr int KC = K / 32;
  constexpr int NT = N / 16;
  int wave = threadIdx.x >> 6;
  int lane = threadIdx.x & 63;
  int row0 = blockIdx.x * 64 + wave * 16;
  if (row0 >= NN) return;
  int m = lane & 15, quad = lane >> 4;
  int arow = row0 + m;

  short8 ah[KC], al[KC];
  const unsigned short* ap = Ahi + (size_t)arow * K + quad * 8;
  const unsigned short* alp = Alo + (size_t)arow * K + quad * 8;
#pragma unroll
  for (int c = 0; c < KC; ++c) {
    ah[c] = *(const short8*)(ap + c * 32);
    al[c] = *(const short8*)(alp + c * 32);
  }

  float sv[4];
#pragma unroll
  for (int i = 0; i < 4; ++i) {
    int r = row0 + quad * 4 + i;
    sv[i] = (MODE == 1) ? Svec[r] : rowscale[r];
  }

#pragma unroll 1
  for (int nt = 0; nt < NT; ++nt) {
    floatx4 acc = {0.f, 0.f, 0.f, 0.f};
#pragma unroll
    for (int c = 0; c < KC; ++c) {
      short8 bh = *(const short8*)(Bhi + ((size_t)(nt * KC + c) * 64 + lane) * 8);
      short8 bl = *(const short8*)(Blo + ((size_t)(nt * KC + c) * 64 + lane) * 8);
      acc = __builtin_amdgcn_mfma_f32_16x16x32_bf16(ah[c], bh, acc, 0, 0, 0);
      acc = __builtin_amdgcn_mfma_f32_16x16x32_bf16(ah[c], bl, acc, 0, 0, 0);
      acc = __builtin_amdgcn_mfma_f32_16x16x32_bf16(al[c], bh, acc, 0, 0, 0);
    }
    int c0 = nt * 16 + m;
    if (MODE == 1) {
      float cv = cvec[c0], bb = bias[c0], aa = alpha[c0];
#pragma unroll
      for (int i = 0; i < 4; ++i) {
        int r = row0 + quad * 4 + i;
        float v = acc[i] + sv[i] * cv + bb;
        v = (v >= 0.f) ? v : aa * v;
        unsigned short hi, lo;
        bsplit(v, hi, lo);
        Chi[(size_t)r * N + c0] = hi;
        Clo[(size_t)r * N + c0] = lo;
      }
    } else {
#pragma unroll
      for (int i = 0; i < 4; ++i) {
        int r = row0 + quad * 4 + i;
        Cb[(size_t)r * N + c0] = bf16_rtne(acc[i] * sv[i]);
      }
    }
  }
}

extern "C" void kernel_launch(void* const* d_in, const int* in_sizes, int n_in,
                              void* d_out, int out_size, void* d_ws, size_t ws_size,
                              hipStream_t stream) {
  const float* x = (const float*)d_in[0];
  const int* ei = (const int*)d_in[1];
  const float* idv = (const float*)d_in[2];
  const float* W1 = (const float*)d_in[3];
  const float* b1 = (const float*)d_in[4];
  const float* a1 = (const float*)d_in[5];
  const float* W2 = (const float*)d_in[6];
  const float* b2 = (const float*)d_in[7];
  const float* a2 = (const float*)d_in[8];
  float* out = (float*)d_out;

  char* w = (char*)d_ws;
  size_t off = 0;
  auto alloc = [&](size_t bytes) -> void* {
    void* p = w + off;
    off += bytes;
    off = (off + 255) & ~(size_t)255;
    return p;
  };
  int* bcnt = (int*)alloc((size_t)NBUCK * 4);
  int* bbase = (int*)alloc((size_t)NBUCK * 4);
  int* bcur = (int*)alloc((size_t)NBUCK * 4);
  unsigned* ebuf = (unsigned*)alloc((size_t)NE * 4);
  float* dinv = (float*)alloc((size_t)NN * 4);
  float* Svec = (float*)alloc((size_t)NN * 4);
  int* offs = (int*)alloc((size_t)(NN + 1) * 4);
  int* col = (int*)alloc((size_t)NE * 4);
  float* cvec = (float*)alloc(256 * 4);
  unsigned short* xsb = (unsigned short*)alloc((size_t)NN * 128 * 2);
  unsigned short* aggxhi = (unsigned short*)alloc((size_t)NN * 128 * 2);
  unsigned short* aggxlo = (unsigned short*)alloc((size_t)NN * 128 * 2);
  unsigned short* h1hi = (unsigned short*)alloc((size_t)NN * 256 * 2);
  unsigned short* h1lo = (unsigned short*)alloc((size_t)NN * 256 * 2);
  unsigned short* h2b = (unsigned short*)alloc((size_t)NN * 128 * 2);
  unsigned short* B1hi = (unsigned short*)alloc(128 * 256 * 2);
  unsigned short* B1lo = (unsigned short*)alloc(128 * 256 * 2);
  unsigned short* B2hi = (unsigned short*)alloc(256 * 128 * 2);
  unsigned short* B2lo = (unsigned short*)alloc(256 * 128 * 2);

  zero_small_kernel<<<1, 128, 0, stream>>>(bcnt);
  bucket_count_kernel<<<NSCAT, 256, 0, stream>>>(ei, bcnt);
  bucket_scan_kernel<<<1, 128, 0, stream>>>(bcnt, bbase, bcur);
  bucket_scatter_kernel<<<NSCAT, 256, 0, stream>>>(ei, bcur, ebuf);
  bucket_csr_kernel<<<NBUCK, 256, 0, stream>>>(ebuf, bbase, bcnt, offs, col, dinv);

  svec_kernel<<<(NN + 255) / 256, 256, 0, stream>>>(dinv, offs, col, Svec);
  cvec_kernel<<<1, 256, 0, stream>>>(idv, W1, cvec);
  scale_x_kernel<<<(NN * 32 + 255) / 256, 256, 0, stream>>>(x, dinv, xsb);
  pack_b_kernel<128, 256><<<(128 * 256 + 255) / 256, 256, 0, stream>>>(W1, B1hi, B1lo);
  pack_b_kernel<256, 128><<<(256 * 128 + 255) / 256, 256, 0, stream>>>(W2, B2hi, B2lo);

  // layer-1 aggregate (bf16 gather, fp32 accum) -> split bf16 hi/lo
  agg_kernel<0><<<NN / 4, 256, 0, stream>>>(xsb, dinv, offs, col, nullptr, nullptr,
                                            aggxhi, aggxlo, nullptr);

  // h1 = prelu(aggx@W1 + Svec*cvec + b1) -> bf16 hi/lo
  gemm_mfma_kernel<128, 256, 1><<<(NN + 63) / 64, 256, 0, stream>>>(
      aggxhi, aggxlo, B1hi, B1lo, Svec, cvec, b1, a1, nullptr, h1hi, h1lo, nullptr);

  // h2b = bf16((h1@W2) * dinv[row])
  gemm_mfma_kernel<256, 128, 2><<<(NN + 63) / 64, 256, 0, stream>>>(
      h1hi, h1lo, B2hi, B2lo, nullptr, nullptr, nullptr, nullptr, dinv,
      nullptr, nullptr, h2b);

  // layer-2 aggregate (bf16 gather) + bias + prelu -> fp32 out
  agg_kernel<1><<<NN / 4, 256, 0, stream>>>(h2b, dinv, offs, col, b2, a2,
                                            nullptr, nullptr, out);
}

// Round 8
// 300.704 us; speedup vs baseline: 1.9105x; 1.0309x over previous
//
#include <hip/hip_runtime.h>

// GCN_72971494359045: 2-layer GCNConv(+self-loops, sym-norm) with PReLU.
// N=50000 nodes, E=800000 edges, dims 128(+8 id)->256->128, all fp32.
//
// R7: partition front-end reshaped for occupancy: TILE 8192->2048 (391
// scatter blocks), buckets 98->196 (dst>>8). Deterministic output bases
// via per-tile histogram + per-bucket tile-scan (no global atomics);
// per-bucket serial flush replaced by parallel binary-search flush.

constexpr int NN = 50000;
constexpr int NE = 800000;
constexpr int NBUCK = 196;   // ceil(NN / 256), bucket = dst >> 8
constexpr int TILE = 2048;   // edges per scatter block
constexpr int NSCAT = (NE + TILE - 1) / TILE;  // 391

typedef __attribute__((ext_vector_type(8))) short short8;
typedef __attribute__((ext_vector_type(4))) float floatx4;

__device__ inline void bsplit(float v, unsigned short& hi, unsigned short& lo) {
  unsigned u = __float_as_uint(v);
  hi = (unsigned short)(u >> 16);
  float rem = v - __uint_as_float(u & 0xffff0000u);
  lo = (unsigned short)(__float_as_uint(rem) >> 16);
}

__device__ inline unsigned short bf16_rtne(float v) {
  unsigned u = __float_as_uint(v);
  return (unsigned short)((u + 0x7fffu + ((u >> 16) & 1u)) >> 16);
}

__device__ inline float bflo(unsigned u) { return __uint_as_float(u << 16); }
__device__ inline float bfhi(unsigned u) { return __uint_as_float(u & 0xffff0000u); }

// --- binned CSR build (deterministic, atomic-free bases) ---

__global__ __launch_bounds__(256) void tile_count_kernel(const int* __restrict__ ei,
                                                         int* __restrict__ tilecnt) {
  __shared__ int h[NBUCK];
  int t = threadIdx.x;
  for (int i = t; i < NBUCK; i += 256) h[i] = 0;
  __syncthreads();
  int base = blockIdx.x * TILE;
  int end = base + TILE; if (end > NE) end = NE;
  for (int e = base + t; e < end; e += 256) atomicAdd(&h[ei[NE + e] >> 8], 1);
  __syncthreads();
  for (int i = t; i < NBUCK; i += 256) tilecnt[blockIdx.x * NBUCK + i] = h[i];
}

// Lane b scans its bucket's counts across tiles (coalesced across lanes),
// then a block scan over bucket totals gives bucket bases.
__global__ void tile_scan_kernel(const int* __restrict__ tilecnt, int* __restrict__ tpre,
                                 int* __restrict__ bbase, int* __restrict__ bcnt) {
  __shared__ int sums[256];
  int b = threadIdx.x;  // 256 >= NBUCK
  int run = 0;
  if (b < NBUCK) {
    for (int ti = 0; ti < NSCAT; ++ti) {
      int idx = ti * NBUCK + b;
      int v = tilecnt[idx];
      tpre[idx] = run;
      run += v;
    }
  }
  sums[b] = (b < NBUCK) ? run : 0;
  __syncthreads();
  for (int off = 1; off < 256; off <<= 1) {
    int u = (b >= off) ? sums[b - off] : 0;
    __syncthreads();
    sums[b] += u;
    __syncthreads();
  }
  if (b < NBUCK) {
    bbase[b] = sums[b] - run;
    bcnt[b] = run;
  }
}

// Stage tile in LDS grouped by bucket; flush in parallel (binary search
// for owning bucket). val = (dst&255)<<16 | src (src < 65536).
__global__ __launch_bounds__(256) void bucket_scatter_kernel(
    const int* __restrict__ ei, const int* __restrict__ tilecnt,
    const int* __restrict__ tpre, const int* __restrict__ bbase,
    unsigned* __restrict__ ebuf) {
  __shared__ int lbase[NBUCK], gb[NBUCK], lcur[NBUCK], ssc[256];
  __shared__ unsigned stage[TILE];
  int t = threadIdx.x;
  int tile = blockIdx.x;
  int base = tile * TILE;
  int cntTile = NE - base; if (cntTile > TILE) cntTile = TILE;
  int h = (t < NBUCK) ? tilecnt[tile * NBUCK + t] : 0;
  ssc[t] = h;
  __syncthreads();
  for (int off = 1; off < 256; off <<= 1) {
    int u = (t >= off) ? ssc[t - off] : 0;
    __syncthreads();
    ssc[t] += u;
    __syncthreads();
  }
  if (t < NBUCK) {
    int ex = ssc[t] - h;
    lbase[t] = ex;
    lcur[t] = ex;
    gb[t] = bbase[t] + tpre[tile * NBUCK + t];
  }
  __syncthreads();
  for (int e = base + t; e < base + cntTile; e += 256) {
    int s = ei[e];
    int d = ei[NE + e];
    int b = d >> 8;
    int pos = atomicAdd(&lcur[b], 1);
    stage[pos] = ((unsigned)(d & 255) << 16) | (unsigned)s;
  }
  __syncthreads();
  for (int i = t; i < cntTile; i += 256) {
    int lo = 0, hi = NBUCK - 1;
    while (lo < hi) {
      int mid = (lo + hi + 1) >> 1;
      if (lbase[mid] <= i) lo = mid; else hi = mid - 1;
    }
    ebuf[gb[lo] + (i - lbase[lo])] = stage[i];
  }
}

// One block per bucket (256 nodes): node histogram -> offs/dinv, then
// scatter col into the bucket's contiguous window (L2-resident).
__global__ __launch_bounds__(256) void bucket_csr_kernel(
    const unsigned* __restrict__ ebuf, const int* __restrict__ bbase,
    const int* __restrict__ bcnt, int* __restrict__ offs, int* __restrict__ col,
    float* __restrict__ dinv) {
  __shared__ int cnt[256], cur[256], sums[256];
  int b = blockIdx.x, t = threadIdx.x;
  int node0 = b << 8;
  cnt[t] = 0;
  __syncthreads();
  int g0 = bbase[b], g1 = g0 + bcnt[b];
  for (int i = g0 + t; i < g1; i += 256) atomicAdd(&cnt[ebuf[i] >> 16], 1);
  __syncthreads();
  int c = cnt[t];
  sums[t] = c;
  __syncthreads();
  for (int off = 1; off < 256; off <<= 1) {
    int u = (t >= off) ? sums[t - off] : 0;
    __syncthreads();
    sums[t] += u;
    __syncthreads();
  }
  int ex = sums[t] - c;
  cur[t] = ex;
  int node = node0 + t;
  if (node < NN) {
    offs[node] = g0 + ex;
    dinv[node] = rsqrtf((float)(c + 1));
  }
  __syncthreads();
  for (int i = g0 + t; i < g1; i += 256) {
    unsigned v = ebuf[i];
    int pos = atomicAdd(&cur[v >> 16], 1);
    col[g0 + pos] = (int)(v & 0xffffu);
  }
  if (b == 0 && t == 0) offs[NN] = NE;
}

// Svec[d] = dd*(dd + sum_{in-edges} dinv[s])
__global__ void svec_kernel(const float* __restrict__ dinv, const int* __restrict__ offs,
                            const int* __restrict__ col, float* __restrict__ Svec) {
  int d = blockIdx.x * blockDim.x + threadIdx.x;
  if (d >= NN) return;
  float s = 0.f;
  int end = offs[d + 1];
  for (int p = offs[d]; p < end; ++p) s += dinv[col[p]];
  float dd = dinv[d];
  Svec[d] = dd * (dd + s);
}

__global__ void cvec_kernel(const float* __restrict__ idv, const float* __restrict__ W1,
                            float* __restrict__ cvec) {
  int m = threadIdx.x;  // 256
  float c = 0.f;
#pragma unroll
  for (int j = 0; j < 8; ++j) c += idv[j] * W1[(128 + j) * 256 + m];
  cvec[m] = c;
}

// xsb[n,:] = bf16(x[n,:] * dinv[n])
__global__ void scale_x_kernel(const float* __restrict__ x, const float* __restrict__ dinv,
                               unsigned short* __restrict__ xsb) {
  int i = blockIdx.x * blockDim.x + threadIdx.x;  // over NN*32 float4s
  if (i < NN * 32) {
    float dd = dinv[i >> 5];
    float4 v = ((const float4*)x)[i];
    ushort4 o;
    o.x = bf16_rtne(v.x * dd);
    o.y = bf16_rtne(v.y * dd);
    o.z = bf16_rtne(v.z * dd);
    o.w = bf16_rtne(v.w * dd);
    ((ushort4*)xsb)[i] = o;
  }
}

// Pack W[K x N] (fp32, row-major) into MFMA B-fragment order, split hi/lo.
template <int K, int N>
__global__ void pack_b_kernel(const float* __restrict__ W, unsigned short* __restrict__ Bhi,
                              unsigned short* __restrict__ Blo) {
  int id = blockIdx.x * 256 + threadIdx.x;
  if (id >= K * N) return;
  constexpr int KC = K / 32;
  int j = id & 7;
  int lane = (id >> 3) & 63;
  int rest = id >> 9;
  int c = rest % KC;
  int nt = rest / KC;
  int k = c * 32 + (lane >> 4) * 8 + j;
  int n = nt * 16 + (lane & 15);
  unsigned short hi, lo;
  bsplit(W[(size_t)k * N + n], hi, lo);
  Bhi[id] = hi;
  Blo[id] = lo;
}

// Wave per node; 32 lanes x 4 bf16 (uint2) cover the 128-wide row; two
// 32-lane halves take alternating edges, x4 unroll => 8 row-loads in flight.
// MODE 0 (layer1): out = dd*(self+sum) -> split bf16 hi/lo (for GEMM A).
// MODE 1 (layer2): out = prelu(dd*(self+sum)+b, a) -> fp32 final output.
template <int MODE>
__global__ __launch_bounds__(256) void agg_kernel(
    const unsigned short* __restrict__ in, const float* __restrict__ dinv,
    const int* __restrict__ offs, const int* __restrict__ col,
    const float* __restrict__ bias, const float* __restrict__ alpha,
    unsigned short* __restrict__ outhi, unsigned short* __restrict__ outlo,
    float* __restrict__ outf) {
  const uint2* inb = (const uint2*)in;  // row = 32 uint2 (128 bf16)
  int t = threadIdx.x;
  int node = blockIdx.x * 4 + (t >> 6);
  int lane = t & 63;
  int r = lane & 31;
  int half = lane >> 5;
  int beg = offs[node], end = offs[node + 1];

  float4 a0 = make_float4(0.f, 0.f, 0.f, 0.f);
  float4 a1 = make_float4(0.f, 0.f, 0.f, 0.f);
  int p = beg + half;
  for (; p + 6 < end; p += 8) {
    int s0 = col[p];
    int s1 = col[p + 2];
    int s2 = col[p + 4];
    int s3 = col[p + 6];
    uint2 v0 = inb[(size_t)s0 * 32 + r];
    uint2 v1 = inb[(size_t)s1 * 32 + r];
    uint2 v2 = inb[(size_t)s2 * 32 + r];
    uint2 v3 = inb[(size_t)s3 * 32 + r];
    a0.x += bflo(v0.x); a0.y += bfhi(v0.x); a0.z += bflo(v0.y); a0.w += bfhi(v0.y);
    a1.x += bflo(v1.x); a1.y += bfhi(v1.x); a1.z += bflo(v1.y); a1.w += bfhi(v1.y);
    a0.x += bflo(v2.x); a0.y += bfhi(v2.x); a0.z += bflo(v2.y); a0.w += bfhi(v2.y);
    a1.x += bflo(v3.x); a1.y += bfhi(v3.x); a1.z += bflo(v3.y); a1.w += bfhi(v3.y);
  }
  for (; p < end; p += 2) {
    uint2 v0 = inb[(size_t)col[p] * 32 + r];
    a0.x += bflo(v0.x); a0.y += bfhi(v0.x); a0.z += bflo(v0.y); a0.w += bfhi(v0.y);
  }
  float4 acc = make_float4(a0.x + a1.x, a0.y + a1.y, a0.z + a1.z, a0.w + a1.w);
  acc.x += __shfl_xor(acc.x, 32);
  acc.y += __shfl_xor(acc.y, 32);
  acc.z += __shfl_xor(acc.z, 32);
  acc.w += __shfl_xor(acc.w, 32);

  float dd = dinv[node];
  if (half == 0) {
    uint2 sv = inb[(size_t)node * 32 + r];
    acc.x = dd * (acc.x + bflo(sv.x));
    acc.y = dd * (acc.y + bfhi(sv.x));
    acc.z = dd * (acc.z + bflo(sv.y));
    acc.w = dd * (acc.w + bfhi(sv.y));
    if (MODE == 0) {
      ushort4 h4, l4;
      bsplit(acc.x, h4.x, l4.x);
      bsplit(acc.y, h4.y, l4.y);
      bsplit(acc.z, h4.z, l4.z);
      bsplit(acc.w, h4.w, l4.w);
      ((ushort4*)outhi)[(size_t)node * 32 + r] = h4;
      ((ushort4*)outlo)[(size_t)node * 32 + r] = l4;
    } else {
      float4 b = ((const float4*)bias)[r];
      float4 al = ((const float4*)alpha)[r];
      acc.x += b.x; acc.y += b.y; acc.z += b.z; acc.w += b.w;
      acc.x = (acc.x >= 0.f) ? acc.x : al.x * acc.x;
      acc.y = (acc.y >= 0.f) ? acc.y : al.y * acc.y;
      acc.z = (acc.z >= 0.f) ? acc.z : al.z * acc.z;
      acc.w = (acc.w >= 0.f) ? acc.w : al.w * acc.w;
      ((float4*)outf)[(size_t)node * 32 + r] = acc;
    }
  }
}

// Split-bf16 MFMA GEMM: C[M,N] = (Ahi+Alo)[M,K] @ (Bhi+Blo)[K,N], 3-term.
// MODE 1: v = prelu(acc + Svec[r]*cvec[c] + bias[c], alpha[c]) -> Chi/Clo bf16.
// MODE 2: v = acc * rowscale[r] -> Cb bf16 (feeds the layer-2 gather).
template <int K, int N, int MODE>
__global__ __launch_bounds__(256) void gemm_mfma_kernel(
    const unsigned short* __restrict__ Ahi, const unsigned short* __restrict__ Alo,
    const unsigned short* __restrict__ Bhi, const unsigned short* __restrict__ Blo,
    const float* __restrict__ Svec, const float* __restrict__ cvec,
    const float* __restrict__ bias, const float* __restrict__ alpha,
    const float* __restrict__ rowscale,
    unsigned short* __restrict__ Chi, unsigned short* __restrict__ Clo,
    unsigned short* __restrict__ Cb) {
  constexpr int KC = K / 32;
  constexpr int NT = N / 16;
  int wave = threadIdx.x >> 6;
  int lane = threadIdx.x & 63;
  int row0 = blockIdx.x * 64 + wave * 16;
  if (row0 >= NN) return;
  int m = lane & 15, quad = lane >> 4;
  int arow = row0 + m;

  short8 ah[KC], al[KC];
  const unsigned short* ap = Ahi + (size_t)arow * K + quad * 8;
  const unsigned short* alp = Alo + (size_t)arow * K + quad * 8;
#pragma unroll
  for (int c = 0; c < KC; ++c) {
    ah[c] = *(const short8*)(ap + c * 32);
    al[c] = *(const short8*)(alp + c * 32);
  }

  float sv[4];
#pragma unroll
  for (int i = 0; i < 4; ++i) {
    int r = row0 + quad * 4 + i;
    sv[i] = (MODE == 1) ? Svec[r] : rowscale[r];
  }

#pragma unroll 1
  for (int nt = 0; nt < NT; ++nt) {
    floatx4 acc = {0.f, 0.f, 0.f, 0.f};
#pragma unroll
    for (int c = 0; c < KC; ++c) {
      short8 bh = *(const short8*)(Bhi + ((size_t)(nt * KC + c) * 64 + lane) * 8);
      short8 bl = *(const short8*)(Blo + ((size_t)(nt * KC + c) * 64 + lane) * 8);
      acc = __builtin_amdgcn_mfma_f32_16x16x32_bf16(ah[c], bh, acc, 0, 0, 0);
      acc = __builtin_amdgcn_mfma_f32_16x16x32_bf16(ah[c], bl, acc, 0, 0, 0);
      acc = __builtin_amdgcn_mfma_f32_16x16x32_bf16(al[c], bh, acc, 0, 0, 0);
    }
    int c0 = nt * 16 + m;
    if (MODE == 1) {
      float cv = cvec[c0], bb = bias[c0], aa = alpha[c0];
#pragma unroll
      for (int i = 0; i < 4; ++i) {
        int r = row0 + quad * 4 + i;
        float v = acc[i] + sv[i] * cv + bb;
        v = (v >= 0.f) ? v : aa * v;
        unsigned short hi, lo;
        bsplit(v, hi, lo);
        Chi[(size_t)r * N + c0] = hi;
        Clo[(size_t)r * N + c0] = lo;
      }
    } else {
#pragma unroll
      for (int i = 0; i < 4; ++i) {
        int r = row0 + quad * 4 + i;
        Cb[(size_t)r * N + c0] = bf16_rtne(acc[i] * sv[i]);
      }
    }
  }
}

extern "C" void kernel_launch(void* const* d_in, const int* in_sizes, int n_in,
                              void* d_out, int out_size, void* d_ws, size_t ws_size,
                              hipStream_t stream) {
  const float* x = (const float*)d_in[0];
  const int* ei = (const int*)d_in[1];
  const float* idv = (const float*)d_in[2];
  const float* W1 = (const float*)d_in[3];
  const float* b1 = (const float*)d_in[4];
  const float* a1 = (const float*)d_in[5];
  const float* W2 = (const float*)d_in[6];
  const float* b2 = (const float*)d_in[7];
  const float* a2 = (const float*)d_in[8];
  float* out = (float*)d_out;

  char* w = (char*)d_ws;
  size_t off = 0;
  auto alloc = [&](size_t bytes) -> void* {
    void* p = w + off;
    off += bytes;
    off = (off + 255) & ~(size_t)255;
    return p;
  };
  int* tilecnt = (int*)alloc((size_t)NSCAT * NBUCK * 4);
  int* tpre = (int*)alloc((size_t)NSCAT * NBUCK * 4);
  int* bbase = (int*)alloc((size_t)NBUCK * 4);
  int* bcnt = (int*)alloc((size_t)NBUCK * 4);
  unsigned* ebuf = (unsigned*)alloc((size_t)NE * 4);
  float* dinv = (float*)alloc((size_t)NN * 4);
  float* Svec = (float*)alloc((size_t)NN * 4);
  int* offs = (int*)alloc((size_t)(NN + 1) * 4);
  int* col = (int*)alloc((size_t)NE * 4);
  float* cvec = (float*)alloc(256 * 4);
  unsigned short* xsb = (unsigned short*)alloc((size_t)NN * 128 * 2);
  unsigned short* aggxhi = (unsigned short*)alloc((size_t)NN * 128 * 2);
  unsigned short* aggxlo = (unsigned short*)alloc((size_t)NN * 128 * 2);
  unsigned short* h1hi = (unsigned short*)alloc((size_t)NN * 256 * 2);
  unsigned short* h1lo = (unsigned short*)alloc((size_t)NN * 256 * 2);
  unsigned short* h2b = (unsigned short*)alloc((size_t)NN * 128 * 2);
  unsigned short* B1hi = (unsigned short*)alloc(128 * 256 * 2);
  unsigned short* B1lo = (unsigned short*)alloc(128 * 256 * 2);
  unsigned short* B2hi = (unsigned short*)alloc(256 * 128 * 2);
  unsigned short* B2lo = (unsigned short*)alloc(256 * 128 * 2);

  tile_count_kernel<<<NSCAT, 256, 0, stream>>>(ei, tilecnt);
  tile_scan_kernel<<<1, 256, 0, stream>>>(tilecnt, tpre, bbase, bcnt);
  bucket_scatter_kernel<<<NSCAT, 256, 0, stream>>>(ei, tilecnt, tpre, bbase, ebuf);
  bucket_csr_kernel<<<NBUCK, 256, 0, stream>>>(ebuf, bbase, bcnt, offs, col, dinv);

  svec_kernel<<<(NN + 255) / 256, 256, 0, stream>>>(dinv, offs, col, Svec);
  cvec_kernel<<<1, 256, 0, stream>>>(idv, W1, cvec);
  scale_x_kernel<<<(NN * 32 + 255) / 256, 256, 0, stream>>>(x, dinv, xsb);
  pack_b_kernel<128, 256><<<(128 * 256 + 255) / 256, 256, 0, stream>>>(W1, B1hi, B1lo);
  pack_b_kernel<256, 128><<<(256 * 128 + 255) / 256, 256, 0, stream>>>(W2, B2hi, B2lo);

  // layer-1 aggregate (bf16 gather, fp32 accum) -> split bf16 hi/lo
  agg_kernel<0><<<NN / 4, 256, 0, stream>>>(xsb, dinv, offs, col, nullptr, nullptr,
                                            aggxhi, aggxlo, nullptr);

  // h1 = prelu(aggx@W1 + Svec*cvec + b1) -> bf16 hi/lo
  gemm_mfma_kernel<128, 256, 1><<<(NN + 63) / 64, 256, 0, stream>>>(
      aggxhi, aggxlo, B1hi, B1lo, Svec, cvec, b1, a1, nullptr, h1hi, h1lo, nullptr);

  // h2b = bf16((h1@W2) * dinv[row])
  gemm_mfma_kernel<256, 128, 2><<<(NN + 63) / 64, 256, 0, stream>>>(
      h1hi, h1lo, B2hi, B2lo, nullptr, nullptr, nullptr, nullptr, dinv,
      nullptr, nullptr, h2b);

  // layer-2 aggregate (bf16 gather) + bias + prelu -> fp32 out
  agg_kernel<1><<<NN / 4, 256, 0, stream>>>(h2b, dinv, offs, col, b2, a2,
                                            nullptr, nullptr, out);
}

// Round 9
// 272.341 us; speedup vs baseline: 2.1095x; 1.1041x over previous
//
#include <hip/hip_runtime.h>

// GCN_72971494359045: 2-layer GCNConv(+self-loops, sym-norm) with PReLU.
// N=50000 nodes, E=800000 edges, dims 128(+8 id)->256->128, all fp32.
//
// R8: (1) tile_scan parallelized (196-block per-bucket scans + tiny base
// scan) -- kills a 1-block 391-iteration serial loop; (2) agg gather main
// tier = 8 edges/half-wave (16 loads in flight/wave); (3) kernel fusion:
// cvec+pack_b -> prep_weights, scale_x+svec -> post_csr (13 -> 10 launches).

constexpr int NN = 50000;
constexpr int NE = 800000;
constexpr int NBUCK = 196;   // ceil(NN / 256), bucket = dst >> 8
constexpr int TILE = 2048;   // edges per scatter block
constexpr int NSCAT = (NE + TILE - 1) / TILE;  // 391

typedef __attribute__((ext_vector_type(8))) short short8;
typedef __attribute__((ext_vector_type(4))) float floatx4;

__device__ inline void bsplit(float v, unsigned short& hi, unsigned short& lo) {
  unsigned u = __float_as_uint(v);
  hi = (unsigned short)(u >> 16);
  float rem = v - __uint_as_float(u & 0xffff0000u);
  lo = (unsigned short)(__float_as_uint(rem) >> 16);
}

__device__ inline unsigned short bf16_rtne(float v) {
  unsigned u = __float_as_uint(v);
  return (unsigned short)((u + 0x7fffu + ((u >> 16) & 1u)) >> 16);
}

__device__ inline float bflo(unsigned u) { return __uint_as_float(u << 16); }
__device__ inline float bfhi(unsigned u) { return __uint_as_float(u & 0xffff0000u); }

// --- binned CSR build (deterministic, atomic-free bases) ---

__global__ __launch_bounds__(256) void tile_count_kernel(const int* __restrict__ ei,
                                                         int* __restrict__ tilecnt) {
  __shared__ int h[NBUCK];
  int t = threadIdx.x;
  for (int i = t; i < NBUCK; i += 256) h[i] = 0;
  __syncthreads();
  int base = blockIdx.x * TILE;
  int end = base + TILE; if (end > NE) end = NE;
  for (int e = base + t; e < end; e += 256) atomicAdd(&h[ei[NE + e] >> 8], 1);
  __syncthreads();
  for (int i = t; i < NBUCK; i += 256) tilecnt[blockIdx.x * NBUCK + i] = h[i];
}

// One block per bucket: exclusive scan of its count across the 391 tiles.
__global__ __launch_bounds__(256) void tile_scan_a_kernel(const int* __restrict__ tilecnt,
                                                          int* __restrict__ tpre,
                                                          int* __restrict__ bcnt) {
  __shared__ int sm[256];
  int b = blockIdx.x, t = threadIdx.x;
  int i0 = 2 * t, i1 = 2 * t + 1;
  int v0 = (i0 < NSCAT) ? tilecnt[i0 * NBUCK + b] : 0;
  int v1 = (i1 < NSCAT) ? tilecnt[i1 * NBUCK + b] : 0;
  int s = v0 + v1;
  sm[t] = s;
  __syncthreads();
  for (int off = 1; off < 256; off <<= 1) {
    int u = (t >= off) ? sm[t - off] : 0;
    __syncthreads();
    sm[t] += u;
    __syncthreads();
  }
  int ex = sm[t] - s;
  if (i0 < NSCAT) tpre[i0 * NBUCK + b] = ex;
  if (i1 < NSCAT) tpre[i1 * NBUCK + b] = ex + v0;
  if (t == 255) bcnt[b] = sm[255];
}

// Tiny scan of the 196 bucket totals -> bucket bases.
__global__ void bucket_base_kernel(const int* __restrict__ bcnt, int* __restrict__ bbase) {
  __shared__ int sm[256];
  int t = threadIdx.x;
  int v = (t < NBUCK) ? bcnt[t] : 0;
  sm[t] = v;
  __syncthreads();
  for (int off = 1; off < 256; off <<= 1) {
    int u = (t >= off) ? sm[t - off] : 0;
    __syncthreads();
    sm[t] += u;
    __syncthreads();
  }
  if (t < NBUCK) bbase[t] = sm[t] - v;
}

// Stage tile in LDS grouped by bucket; flush in parallel (binary search
// for owning bucket). val = (dst&255)<<16 | src (src < 65536).
__global__ __launch_bounds__(256) void bucket_scatter_kernel(
    const int* __restrict__ ei, const int* __restrict__ tilecnt,
    const int* __restrict__ tpre, const int* __restrict__ bbase,
    unsigned* __restrict__ ebuf) {
  __shared__ int lbase[NBUCK], gb[NBUCK], lcur[NBUCK], ssc[256];
  __shared__ unsigned stage[TILE];
  int t = threadIdx.x;
  int tile = blockIdx.x;
  int base = tile * TILE;
  int cntTile = NE - base; if (cntTile > TILE) cntTile = TILE;
  int h = (t < NBUCK) ? tilecnt[tile * NBUCK + t] : 0;
  ssc[t] = h;
  __syncthreads();
  for (int off = 1; off < 256; off <<= 1) {
    int u = (t >= off) ? ssc[t - off] : 0;
    __syncthreads();
    ssc[t] += u;
    __syncthreads();
  }
  if (t < NBUCK) {
    int ex = ssc[t] - h;
    lbase[t] = ex;
    lcur[t] = ex;
    gb[t] = bbase[t] + tpre[tile * NBUCK + t];
  }
  __syncthreads();
  for (int e = base + t; e < base + cntTile; e += 256) {
    int s = ei[e];
    int d = ei[NE + e];
    int b = d >> 8;
    int pos = atomicAdd(&lcur[b], 1);
    stage[pos] = ((unsigned)(d & 255) << 16) | (unsigned)s;
  }
  __syncthreads();
  for (int i = t; i < cntTile; i += 256) {
    int lo = 0, hi = NBUCK - 1;
    while (lo < hi) {
      int mid = (lo + hi + 1) >> 1;
      if (lbase[mid] <= i) lo = mid; else hi = mid - 1;
    }
    ebuf[gb[lo] + (i - lbase[lo])] = stage[i];
  }
}

// One block per bucket (256 nodes): node histogram -> offs/dinv, then
// scatter col into the bucket's contiguous window (L2-resident).
__global__ __launch_bounds__(256) void bucket_csr_kernel(
    const unsigned* __restrict__ ebuf, const int* __restrict__ bbase,
    const int* __restrict__ bcnt, int* __restrict__ offs, int* __restrict__ col,
    float* __restrict__ dinv) {
  __shared__ int cnt[256], cur[256], sums[256];
  int b = blockIdx.x, t = threadIdx.x;
  int node0 = b << 8;
  cnt[t] = 0;
  __syncthreads();
  int g0 = bbase[b], g1 = g0 + bcnt[b];
  for (int i = g0 + t; i < g1; i += 256) atomicAdd(&cnt[ebuf[i] >> 16], 1);
  __syncthreads();
  int c = cnt[t];
  sums[t] = c;
  __syncthreads();
  for (int off = 1; off < 256; off <<= 1) {
    int u = (t >= off) ? sums[t - off] : 0;
    __syncthreads();
    sums[t] += u;
    __syncthreads();
  }
  int ex = sums[t] - c;
  cur[t] = ex;
  int node = node0 + t;
  if (node < NN) {
    offs[node] = g0 + ex;
    dinv[node] = rsqrtf((float)(c + 1));
  }
  __syncthreads();
  for (int i = g0 + t; i < g1; i += 256) {
    unsigned v = ebuf[i];
    int pos = atomicAdd(&cur[v >> 16], 1);
    col[g0 + pos] = (int)(v & 0xffffu);
  }
  if (b == 0 && t == 0) offs[NN] = NE;
}

// Fused: xsb[n,:] = bf16(x[n,:]*dinv[n])  and  Svec[d] = dd*(dd+sum dinv[s]).
__global__ __launch_bounds__(256) void post_csr_kernel(
    const float* __restrict__ x, const float* __restrict__ dinv,
    const int* __restrict__ offs, const int* __restrict__ col,
    unsigned short* __restrict__ xsb, float* __restrict__ Svec) {
  int id = blockIdx.x * 256 + threadIdx.x;
  if (id < NN * 32) {
    float dd = dinv[id >> 5];
    float4 v = ((const float4*)x)[id];
    ushort4 o;
    o.x = bf16_rtne(v.x * dd);
    o.y = bf16_rtne(v.y * dd);
    o.z = bf16_rtne(v.z * dd);
    o.w = bf16_rtne(v.w * dd);
    ((ushort4*)xsb)[id] = o;
  } else {
    int d = id - NN * 32;
    if (d < NN) {
      float s = 0.f;
      int end = offs[d + 1];
      for (int p = offs[d]; p < end; ++p) s += dinv[col[p]];
      float dd = dinv[d];
      Svec[d] = dd * (dd + s);
    }
  }
}

// Pack W[K x N] (fp32, row-major) into MFMA B-fragment order, split hi/lo.
template <int K, int N>
__device__ inline void pack_one(const float* __restrict__ W, unsigned short* __restrict__ Bhi,
                                unsigned short* __restrict__ Blo, int id) {
  constexpr int KC = K / 32;
  int j = id & 7;
  int lane = (id >> 3) & 63;
  int rest = id >> 9;
  int c = rest % KC;
  int nt = rest / KC;
  int k = c * 32 + (lane >> 4) * 8 + j;
  int n = nt * 16 + (lane & 15);
  unsigned short hi, lo;
  bsplit(W[(size_t)k * N + n], hi, lo);
  Bhi[id] = hi;
  Blo[id] = lo;
}

// Fused weight prep: pack W1, pack W2, cvec.
__global__ void prep_weights_kernel(const float* __restrict__ W1, const float* __restrict__ W2,
                                    const float* __restrict__ idv,
                                    unsigned short* __restrict__ B1hi, unsigned short* __restrict__ B1lo,
                                    unsigned short* __restrict__ B2hi, unsigned short* __restrict__ B2lo,
                                    float* __restrict__ cvec) {
  int id = blockIdx.x * 256 + threadIdx.x;
  if (id < 32768) {
    pack_one<128, 256>(W1, B1hi, B1lo, id);
  } else if (id < 65536) {
    pack_one<256, 128>(W2, B2hi, B2lo, id - 32768);
  } else if (id < 65536 + 256) {
    int m = id - 65536;
    float c = 0.f;
#pragma unroll
    for (int j = 0; j < 8; ++j) c += idv[j] * W1[(128 + j) * 256 + m];
    cvec[m] = c;
  }
}

// Wave per node; 32 lanes x 4 bf16 (uint2) cover the 128-wide row; two
// 32-lane halves take alternating edges; main tier = 8 edges/half
// (16 row-loads in flight per wave), then 2- and 1-edge tails.
// MODE 0 (layer1): out = dd*(self+sum) -> split bf16 hi/lo (for GEMM A).
// MODE 1 (layer2): out = prelu(dd*(self+sum)+b, a) -> fp32 final output.
template <int MODE>
__global__ __launch_bounds__(256) void agg_kernel(
    const unsigned short* __restrict__ in, const float* __restrict__ dinv,
    const int* __restrict__ offs, const int* __restrict__ col,
    const float* __restrict__ bias, const float* __restrict__ alpha,
    unsigned short* __restrict__ outhi, unsigned short* __restrict__ outlo,
    float* __restrict__ outf) {
  const uint2* inb = (const uint2*)in;  // row = 32 uint2 (128 bf16)
  int t = threadIdx.x;
  int node = blockIdx.x * 4 + (t >> 6);
  int lane = t & 63;
  int r = lane & 31;
  int half = lane >> 5;
  int beg = offs[node], end = offs[node + 1];

  float4 a0 = make_float4(0.f, 0.f, 0.f, 0.f);
  float4 a1 = make_float4(0.f, 0.f, 0.f, 0.f);
  float4 a2 = make_float4(0.f, 0.f, 0.f, 0.f);
  float4 a3 = make_float4(0.f, 0.f, 0.f, 0.f);
  int p = beg + half;
  for (; p + 14 < end; p += 16) {  // 8 edges per half-wave
    int s0 = col[p];      int s1 = col[p + 2];
    int s2 = col[p + 4];  int s3 = col[p + 6];
    int s4 = col[p + 8];  int s5 = col[p + 10];
    int s6 = col[p + 12]; int s7 = col[p + 14];
    uint2 v0 = inb[(size_t)s0 * 32 + r];
    uint2 v1 = inb[(size_t)s1 * 32 + r];
    uint2 v2 = inb[(size_t)s2 * 32 + r];
    uint2 v3 = inb[(size_t)s3 * 32 + r];
    uint2 v4 = inb[(size_t)s4 * 32 + r];
    uint2 v5 = inb[(size_t)s5 * 32 + r];
    uint2 v6 = inb[(size_t)s6 * 32 + r];
    uint2 v7 = inb[(size_t)s7 * 32 + r];
    a0.x += bflo(v0.x); a0.y += bfhi(v0.x); a0.z += bflo(v0.y); a0.w += bfhi(v0.y);
    a1.x += bflo(v1.x); a1.y += bfhi(v1.x); a1.z += bflo(v1.y); a1.w += bfhi(v1.y);
    a2.x += bflo(v2.x); a2.y += bfhi(v2.x); a2.z += bflo(v2.y); a2.w += bfhi(v2.y);
    a3.x += bflo(v3.x); a3.y += bfhi(v3.x); a3.z += bflo(v3.y); a3.w += bfhi(v3.y);
    a0.x += bflo(v4.x); a0.y += bfhi(v4.x); a0.z += bflo(v4.y); a0.w += bfhi(v4.y);
    a1.x += bflo(v5.x); a1.y += bfhi(v5.x); a1.z += bflo(v5.y); a1.w += bfhi(v5.y);
    a2.x += bflo(v6.x); a2.y += bfhi(v6.x); a2.z += bflo(v6.y); a2.w += bfhi(v6.y);
    a3.x += bflo(v7.x); a3.y += bfhi(v7.x); a3.z += bflo(v7.y); a3.w += bfhi(v7.y);
  }
  for (; p + 2 < end; p += 4) {  // 2 edges
    int s0 = col[p];
    int s1 = col[p + 2];
    uint2 v0 = inb[(size_t)s0 * 32 + r];
    uint2 v1 = inb[(size_t)s1 * 32 + r];
    a0.x += bflo(v0.x); a0.y += bfhi(v0.x); a0.z += bflo(v0.y); a0.w += bfhi(v0.y);
    a1.x += bflo(v1.x); a1.y += bfhi(v1.x); a1.z += bflo(v1.y); a1.w += bfhi(v1.y);
  }
  if (p < end) {
    uint2 v0 = inb[(size_t)col[p] * 32 + r];
    a0.x += bflo(v0.x); a0.y += bfhi(v0.x); a0.z += bflo(v0.y); a0.w += bfhi(v0.y);
  }
  float4 acc = make_float4((a0.x + a1.x) + (a2.x + a3.x), (a0.y + a1.y) + (a2.y + a3.y),
                           (a0.z + a1.z) + (a2.z + a3.z), (a0.w + a1.w) + (a2.w + a3.w));
  acc.x += __shfl_xor(acc.x, 32);
  acc.y += __shfl_xor(acc.y, 32);
  acc.z += __shfl_xor(acc.z, 32);
  acc.w += __shfl_xor(acc.w, 32);

  float dd = dinv[node];
  if (half == 0) {
    uint2 sv = inb[(size_t)node * 32 + r];
    acc.x = dd * (acc.x + bflo(sv.x));
    acc.y = dd * (acc.y + bfhi(sv.x));
    acc.z = dd * (acc.z + bflo(sv.y));
    acc.w = dd * (acc.w + bfhi(sv.y));
    if (MODE == 0) {
      ushort4 h4, l4;
      bsplit(acc.x, h4.x, l4.x);
      bsplit(acc.y, h4.y, l4.y);
      bsplit(acc.z, h4.z, l4.z);
      bsplit(acc.w, h4.w, l4.w);
      ((ushort4*)outhi)[(size_t)node * 32 + r] = h4;
      ((ushort4*)outlo)[(size_t)node * 32 + r] = l4;
    } else {
      float4 b = ((const float4*)bias)[r];
      float4 al = ((const float4*)alpha)[r];
      acc.x += b.x; acc.y += b.y; acc.z += b.z; acc.w += b.w;
      acc.x = (acc.x >= 0.f) ? acc.x : al.x * acc.x;
      acc.y = (acc.y >= 0.f) ? acc.y : al.y * acc.y;
      acc.z = (acc.z >= 0.f) ? acc.z : al.z * acc.z;
      acc.w = (acc.w >= 0.f) ? acc.w : al.w * acc.w;
      ((float4*)outf)[(size_t)node * 32 + r] = acc;
    }
  }
}

// Split-bf16 MFMA GEMM: C[M,N] = (Ahi+Alo)[M,K] @ (Bhi+Blo)[K,N], 3-term.
// MODE 1: v = prelu(acc + Svec[r]*cvec[c] + bias[c], alpha[c]) -> Chi/Clo bf16.
// MODE 2: v = acc * rowscale[r] -> Cb bf16 (feeds the layer-2 gather).
template <int K, int N, int MODE>
__global__ __launch_bounds__(256) void gemm_mfma_kernel(
    const unsigned short* __restrict__ Ahi, const unsigned short* __restrict__ Alo,
    const unsigned short* __restrict__ Bhi, const unsigned short* __restrict__ Blo,
    const float* __restrict__ Svec, const float* __restrict__ cvec,
    const float* __restrict__ bias, const float* __restrict__ alpha,
    const float* __restrict__ rowscale,
    unsigned short* __restrict__ Chi, unsigned short* __restrict__ Clo,
    unsigned short* __restrict__ Cb) {
  constexpr int KC = K / 32;
  constexpr int NT = N / 16;
  int wave = threadIdx.x >> 6;
  int lane = threadIdx.x & 63;
  int row0 = blockIdx.x * 64 + wave * 16;
  if (row0 >= NN) return;
  int m = lane & 15, quad = lane >> 4;
  int arow = row0 + m;

  short8 ah[KC], al[KC];
  const unsigned short* ap = Ahi + (size_t)arow * K + quad * 8;
  const unsigned short* alp = Alo + (size_t)arow * K + quad * 8;
#pragma unroll
  for (int c = 0; c < KC; ++c) {
    ah[c] = *(const short8*)(ap + c * 32);
    al[c] = *(const short8*)(alp + c * 32);
  }

  float sv[4];
#pragma unroll
  for (int i = 0; i < 4; ++i) {
    int r = row0 + quad * 4 + i;
    sv[i] = (MODE == 1) ? Svec[r] : rowscale[r];
  }

#pragma unroll 1
  for (int nt = 0; nt < NT; ++nt) {
    floatx4 acc = {0.f, 0.f, 0.f, 0.f};
#pragma unroll
    for (int c = 0; c < KC; ++c) {
      short8 bh = *(const short8*)(Bhi + ((size_t)(nt * KC + c) * 64 + lane) * 8);
      short8 bl = *(const short8*)(Blo + ((size_t)(nt * KC + c) * 64 + lane) * 8);
      acc = __builtin_amdgcn_mfma_f32_16x16x32_bf16(ah[c], bh, acc, 0, 0, 0);
      acc = __builtin_amdgcn_mfma_f32_16x16x32_bf16(ah[c], bl, acc, 0, 0, 0);
      acc = __builtin_amdgcn_mfma_f32_16x16x32_bf16(al[c], bh, acc, 0, 0, 0);
    }
    int c0 = nt * 16 + m;
    if (MODE == 1) {
      float cv = cvec[c0], bb = bias[c0], aa = alpha[c0];
#pragma unroll
      for (int i = 0; i < 4; ++i) {
        int r = row0 + quad * 4 + i;
        float v = acc[i] + sv[i] * cv + bb;
        v = (v >= 0.f) ? v : aa * v;
        unsigned short hi, lo;
        bsplit(v, hi, lo);
        Chi[(size_t)r * N + c0] = hi;
        Clo[(size_t)r * N + c0] = lo;
      }
    } else {
#pragma unroll
      for (int i = 0; i < 4; ++i) {
        int r = row0 + quad * 4 + i;
        Cb[(size_t)r * N + c0] = bf16_rtne(acc[i] * sv[i]);
      }
    }
  }
}

extern "C" void kernel_launch(void* const* d_in, const int* in_sizes, int n_in,
                              void* d_out, int out_size, void* d_ws, size_t ws_size,
                              hipStream_t stream) {
  const float* x = (const float*)d_in[0];
  const int* ei = (const int*)d_in[1];
  const float* idv = (const float*)d_in[2];
  const float* W1 = (const float*)d_in[3];
  const float* b1 = (const float*)d_in[4];
  const float* a1 = (const float*)d_in[5];
  const float* W2 = (const float*)d_in[6];
  const float* b2 = (const float*)d_in[7];
  const float* a2 = (const float*)d_in[8];
  float* out = (float*)d_out;

  char* w = (char*)d_ws;
  size_t off = 0;
  auto alloc = [&](size_t bytes) -> void* {
    void* p = w + off;
    off += bytes;
    off = (off + 255) & ~(size_t)255;
    return p;
  };
  int* tilecnt = (int*)alloc((size_t)NSCAT * NBUCK * 4);
  int* tpre = (int*)alloc((size_t)NSCAT * NBUCK * 4);
  int* bbase = (int*)alloc((size_t)NBUCK * 4);
  int* bcnt = (int*)alloc((size_t)NBUCK * 4);
  unsigned* ebuf = (unsigned*)alloc((size_t)NE * 4);
  float* dinv = (float*)alloc((size_t)NN * 4);
  float* Svec = (float*)alloc((size_t)NN * 4);
  int* offs = (int*)alloc((size_t)(NN + 1) * 4);
  int* col = (int*)alloc((size_t)NE * 4);
  float* cvec = (float*)alloc(256 * 4);
  unsigned short* xsb = (unsigned short*)alloc((size_t)NN * 128 * 2);
  unsigned short* aggxhi = (unsigned short*)alloc((size_t)NN * 128 * 2);
  unsigned short* aggxlo = (unsigned short*)alloc((size_t)NN * 128 * 2);
  unsigned short* h1hi = (unsigned short*)alloc((size_t)NN * 256 * 2);
  unsigned short* h1lo = (unsigned short*)alloc((size_t)NN * 256 * 2);
  unsigned short* h2b = (unsigned short*)alloc((size_t)NN * 128 * 2);
  unsigned short* B1hi = (unsigned short*)alloc(128 * 256 * 2);
  unsigned short* B1lo = (unsigned short*)alloc(128 * 256 * 2);
  unsigned short* B2hi = (unsigned short*)alloc(256 * 128 * 2);
  unsigned short* B2lo = (unsigned short*)alloc(256 * 128 * 2);

  tile_count_kernel<<<NSCAT, 256, 0, stream>>>(ei, tilecnt);
  tile_scan_a_kernel<<<NBUCK, 256, 0, stream>>>(tilecnt, tpre, bcnt);
  bucket_base_kernel<<<1, 256, 0, stream>>>(bcnt, bbase);
  bucket_scatter_kernel<<<NSCAT, 256, 0, stream>>>(ei, tilecnt, tpre, bbase, ebuf);
  bucket_csr_kernel<<<NBUCK, 256, 0, stream>>>(ebuf, bbase, bcnt, offs, col, dinv);

  prep_weights_kernel<<<(65536 + 256 + 255) / 256, 256, 0, stream>>>(
      W1, W2, idv, B1hi, B1lo, B2hi, B2lo, cvec);
  post_csr_kernel<<<(NN * 32 + NN + 255) / 256, 256, 0, stream>>>(
      x, dinv, offs, col, xsb, Svec);

  // layer-1 aggregate (bf16 gather, fp32 accum) -> split bf16 hi/lo
  agg_kernel<0><<<NN / 4, 256, 0, stream>>>(xsb, dinv, offs, col, nullptr, nullptr,
                                            aggxhi, aggxlo, nullptr);

  // h1 = prelu(aggx@W1 + Svec*cvec + b1) -> bf16 hi/lo
  gemm_mfma_kernel<128, 256, 1><<<(NN + 63) / 64, 256, 0, stream>>>(
      aggxhi, aggxlo, B1hi, B1lo, Svec, cvec, b1, a1, nullptr, h1hi, h1lo, nullptr);

  // h2b = bf16((h1@W2) * dinv[row])
  gemm_mfma_kernel<256, 128, 2><<<(NN + 63) / 64, 256, 0, stream>>>(
      h1hi, h1lo, B2hi, B2lo, nullptr, nullptr, nullptr, nullptr, dinv,
      nullptr, nullptr, h2b);

  // layer-2 aggregate (bf16 gather) + bias + prelu -> fp32 out
  agg_kernel<1><<<NN / 4, 256, 0, stream>>>(h2b, dinv, offs, col, b2, a2,
                                            nullptr, nullptr, out);
}